// Round 8
// baseline (288.942 us; speedup 1.0000x reference)
//
#include <hip/hip_runtime.h>
#include <cstdint>
#include <cstddef>

using bf16   = __bf16;
using bf16x8 = __bf16 __attribute__((ext_vector_type(8)));
using f32x4  = float  __attribute__((ext_vector_type(4)));
using u16    = unsigned short;
using ushort8 = __attribute__((ext_vector_type(8))) unsigned short;

#define MFMA16(a, b, c) __builtin_amdgcn_mfma_f32_16x16x32_bf16(a, b, c, 0, 0, 0)

__device__ __forceinline__ u16 f2bf(float f) {
  union { float f; unsigned u; } v; v.f = f;
  unsigned r = v.u + 0x7fffu + ((v.u >> 16) & 1u);
  return (u16)(r >> 16);
}
__device__ __forceinline__ u16 bfc(float f) {
  union { float f; unsigned u; } v; v.f = f;
  return (u16)((v.u + 0x8000u) >> 16);
}
__device__ __forceinline__ float b2f(u16 h) {
  union { unsigned u; float f; } v; v.u = ((unsigned)h) << 16; return v.f;
}
__device__ __forceinline__ bf16x8 ldb8(const u16* p) { return *(const bf16x8*)p; }
__device__ __forceinline__ float red_sum16(float v) {
  v += __shfl_xor(v, 1, 64); v += __shfl_xor(v, 2, 64);
  v += __shfl_xor(v, 4, 64); v += __shfl_xor(v, 8, 64);
  return v;
}
__device__ __forceinline__ void gll16(const u16* g, u16* l) {
  __builtin_amdgcn_global_load_lds(
      (const __attribute__((address_space(1))) void*)g,
      (__attribute__((address_space(3))) void*)l, 16, 0, 0);
}

#define QSCALE 0.09016844005556021f  // C^-0.5 * log2(e)

// ---------- prep: weights -> MFMA B-fragment layouts, read direct-from-global by k_fused.
// Fragment file: idx = ((f*KK + kk)*64 + lane)*8 + e  holds  W[out = f*16 + (lane&15)]
//                [k = kk*32 + (lane>>4)*8 + e].  (Same mapping the old sW LDS reads used.)
__global__ void k_prep(const float* __restrict__ kv_w2, const float* __restrict__ kv_w3,
                       const float* __restrict__ kv_w4, const float* __restrict__ q_w,
                       const float* __restrict__ proj_w,
                       u16* __restrict__ Wt2, u16* __restrict__ Wt3, u16* __restrict__ Wt4,
                       u16* __restrict__ Qw, u16* __restrict__ Pww) {
  int idx = blockIdx.x * 256 + threadIdx.x;
  if (idx < 32768) {                    // Wf2: K=128 (KK=4), N=256; kv_w2 is [k][n]
    int j = idx, e = j & 7, l = (j >> 3) & 63, t = j >> 9;
    int kk = t & 3, f = t >> 2;
    Wt2[j] = f2bf(kv_w2[(kk * 32 + (l >> 4) * 8 + e) * 256 + f * 16 + (l & 15)]);
  } else if (idx < 98304) {             // Wf3: K=256 (KK=8), N=256; kv_w3 is [k][n]
    int j = idx - 32768, e = j & 7, l = (j >> 3) & 63, t = j >> 9;
    int kk = t & 7, f = t >> 3;
    Wt3[j] = f2bf(kv_w3[(kk * 32 + (l >> 4) * 8 + e) * 256 + f * 16 + (l & 15)]);
  } else if (idx < 229376) {            // Wf4: K=256 (KK=8), N=512 (f4=h*16+f); kv_w4 [k][n]
    int j = idx - 98304, e = j & 7, l = (j >> 3) & 63, t = j >> 9;
    int kk = t & 7, f4 = t >> 3;
    Wt4[j] = f2bf(kv_w4[(kk * 32 + (l >> 4) * 8 + e) * 512 + f4 * 16 + (l & 15)]);
  } else if (idx < 294912) {            // Qf: K=256 (k8=kc*2+kk), N=256; q_w is [o][c]
    int j = idx - 229376, e = j & 7, l = (j >> 3) & 63, t = j >> 9;
    int k8 = t & 7, f = t >> 3;
    Qw[j] = f2bf(q_w[(f * 16 + (l & 15)) * 256 + k8 * 32 + (l >> 4) * 8 + e]);
  } else if (idx < 360448) {
    int j = idx - 294912;
    Pww[j] = f2bf(proj_w[j]);
  }
}

// ---------- fused MLP helpers (act is WAVE-PRIVATE rows -> zero barriers) ----------
__device__ __forceinline__ void ln_store(f32x4* acc, const float* __restrict__ bias,
    const float* __restrict__ g, const float* __restrict__ bb, u16* act,
    int w, int quad, int l16) {
  #pragma unroll
  for (int f = 0; f < 16; ++f) {
    float bv = bias[f * 16 + l16];
    acc[f][0] += bv; acc[f][1] += bv; acc[f][2] += bv; acc[f][3] += bv;
  }
  #pragma unroll
  for (int r = 0; r < 4; ++r) {
    float s = 0;
    #pragma unroll
    for (int f = 0; f < 16; ++f) s += acc[f][r];
    s = red_sum16(s);
    float mu = s * (1.f / 256.f);
    float vv = 0;
    #pragma unroll
    for (int f = 0; f < 16; ++f) { float d = acc[f][r] - mu; vv += d * d; }
    vv = red_sum16(vv);
    float inv = rsqrtf(vv * (1.f / 256.f) + 1e-5f);
    int rl = w * 16 + quad * 4 + r;
    #pragma unroll
    for (int f = 0; f < 16; ++f) {
      int col = f * 16 + l16;
      float o = (acc[f][r] - mu) * inv * g[col] + bb[col];
      o = o > 0.f ? o : 0.01f * o;
      act[rl * 264 + col] = f2bf(o);
    }
  }
}

template<int KK>
__device__ __forceinline__ void mlp_layer_g(u16* act, const u16* __restrict__ Wf,
    const float* __restrict__ bias, const float* __restrict__ g, const float* __restrict__ bb,
    int lane, int w, int quad, int l16) {
  bf16x8 af[KK];
  #pragma unroll
  for (int kk = 0; kk < KK; ++kk) af[kk] = ldb8(act + (w * 16 + l16) * 264 + kk * 32 + quad * 8);
  f32x4 z = {0.f, 0.f, 0.f, 0.f};
  f32x4 acc[16];
  const u16* bp = Wf + (size_t)lane * 8;
  #pragma unroll
  for (int f = 0; f < 16; ++f) {
    acc[f] = z;
    #pragma unroll
    for (int kk = 0; kk < KK; ++kk)
      acc[f] = MFMA16(af[kk], ldb8(bp + (size_t)(f * KK + kk) * 512), acc[f]);
  }
  ln_store(acc, bias, g, bb, act, w, quad, l16);
}

__device__ __forceinline__ void mlp_layer4_g(u16* act, const u16* __restrict__ Wf4,
    const float* __restrict__ bias4, u16* __restrict__ Kt, u16* __restrict__ Vt,
    int i0, int lane, int w, int quad, int l16) {
  bf16x8 af[8];
  #pragma unroll
  for (int kk = 0; kk < 8; ++kk) af[kk] = ldb8(act + (w * 16 + l16) * 264 + kk * 32 + quad * 8);
  f32x4 z = {0.f, 0.f, 0.f, 0.f};
  const u16* bp = Wf4 + (size_t)lane * 8;
  for (int h = 0; h < 2; ++h) {
    f32x4 acc[16];
    #pragma unroll
    for (int f = 0; f < 16; ++f) {
      acc[f] = z;
      #pragma unroll
      for (int kk = 0; kk < 8; ++kk)
        acc[f] = MFMA16(af[kk], ldb8(bp + (size_t)((h * 16 + f) * 8 + kk) * 512), acc[f]);
    }
    // epilogue: silu.
    // K: fragment layout, per 32-kv tile, u16 index within the 8192-u16 tile:
    //      kk*1024 + blk*512 + qs*128 + (kv>>1)*8 + e   (blk = kv&1)  [verified round 5]
    // V: fragment layout, natural kv order [verified round 1].
    #pragma unroll
    for (int f = 0; f < 16; ++f) {
      int col = f * 16 + l16;
      float bv = bias4[h * 256 + col];
      if (h == 0) {
        int kk = f >> 1;
        int qs = (f & 1) * 2 + (l16 >> 3);
        int e  = l16 & 7;
        int l16base = (w & 1) * 8 + quad * 2;
        size_t tb = ((size_t)((i0 >> 5) + (w >> 1))) * 8192 + kk * 1024 + qs * 128 + e;
        #pragma unroll
        for (int r = 0; r < 4; ++r) {
          float v = acc[f][r] + bv;
          v = v / (1.f + __expf(-v));
          Kt[tb + (size_t)(r & 1) * 512 + (size_t)(l16base + (r >> 1)) * 8] = f2bf(v);
        }
      } else {
        int rowg0 = i0 + w * 16 + quad * 4;
        int bb2 = rowg0 >> 12;          // batch
        int tt = (rowg0 >> 5) & 127;    // 32-kv tile
        int qv = (rowg0 >> 3) & 3;      // quad within tile
        int e0 = rowg0 & 7;             // element base (0 or 4)
        ushort4 u;
        #pragma unroll
        for (int r = 0; r < 4; ++r) {
          float v = acc[f][r] + bv;
          v = v / (1.f + __expf(-v));
          ((u16*)&u)[r] = f2bf(v);
        }
        size_t off = ((size_t)(bb2 * 128 + tt)) * 8192 + f * 512 + qv * 128 + l16 * 8 + e0;
        *(ushort4*)(Vt + off) = u;
      }
    }
  }
}

// ---------- fused: [blocks 0..255] full KV-MLP per 64-row tile (barrier-free, weights
// direct-from-global fragment files); [256..511] Q-GEMM (Qw direct-from-global) ----------
__global__ __launch_bounds__(256, 2) void k_fused(
    const float* __restrict__ x, const float* __restrict__ w1, const float* __restrict__ bias1,
    const float* __restrict__ g1, const float* __restrict__ bb1,
    const u16* __restrict__ Wt2, const float* __restrict__ bias2,
    const float* __restrict__ g2, const float* __restrict__ bb2,
    const u16* __restrict__ Wt3, const float* __restrict__ bias3,
    const float* __restrict__ g3, const float* __restrict__ bb3,
    const u16* __restrict__ Wt4, const float* __restrict__ bias4,
    const float* __restrict__ y, const u16* __restrict__ Qw,
    const float* __restrict__ qb, const float* __restrict__ dww, const float* __restrict__ dwb,
    u16* __restrict__ Kt, u16* __restrict__ Vt, u16* __restrict__ Qb) {
  __shared__ __align__(16) u16 smem[16896];   // MLP: act[64][264]; Q-GEMM: sY[64][72]
  int tid = threadIdx.x, w = tid >> 6, lane = tid & 63, quad = lane >> 4, l16 = lane & 15;

  if (blockIdx.x < 256) {
    // ===== KV-MLP: rows i0..i0+64 through 4 layers; act rows are wave-private =====
    u16* act = smem;              // [64][264]
    int i0 = blockIdx.x * 64;
    {   // layer 1: scalar -> 128, LN, leaky. Thread: row w*16+(lane>>2), cols (lane&3)*32..
      int rloc = w * 16 + (lane >> 2);
      int c0 = (lane & 3) * 32;
      float xv = x[i0 + rloc];
      float t[32];
      float s = 0.f;
      #pragma unroll
      for (int j = 0; j < 32; ++j) { t[j] = xv * w1[c0 + j] + bias1[c0 + j]; s += t[j]; }
      s += __shfl_xor(s, 1, 64); s += __shfl_xor(s, 2, 64);
      float mu = s * (1.f / 128.f);
      float vv = 0.f;
      #pragma unroll
      for (int j = 0; j < 32; ++j) { float d = t[j] - mu; vv += d * d; }
      vv += __shfl_xor(vv, 1, 64); vv += __shfl_xor(vv, 2, 64);
      float inv = rsqrtf(vv * (1.f / 128.f) + 1e-5f);
      #pragma unroll
      for (int jo = 0; jo < 4; ++jo) {
        ushort8 pk;
        #pragma unroll
        for (int e = 0; e < 8; ++e) {
          int j = jo * 8 + e;
          float o = (t[j] - mu) * inv * g1[c0 + j] + bb1[c0 + j];
          o = o > 0.f ? o : 0.01f * o;
          pk[e] = f2bf(o);
        }
        *(ushort8*)(act + rloc * 264 + c0 + jo * 8) = pk;
      }
    }
    mlp_layer_g<4>(act, Wt2, bias2, g2, bb2, lane, w, quad, l16);
    mlp_layer_g<8>(act, Wt3, bias3, g3, bb3, lane, w, quad, l16);
    mlp_layer4_g(act, Wt4, bias4, Kt, Vt, i0, lane, w, quad, l16);
    return;
  }

  // ===== Q-GEMM partition: 64-row tiles, pre-scaled by QSCALE; Qw direct-from-global =====
  u16* sY = smem;              // [64][72]
  int t = blockIdx.x - 256;
  int b = t >> 6, i0 = (t & 63) * 64;
  f32x4 z = {0.f, 0.f, 0.f, 0.f};
  f32x4 acc[16];
  #pragma unroll
  for (int f = 0; f < 16; ++f) acc[f] = z;
  const u16* qbp = Qw + (size_t)lane * 8;
  for (int kc = 0; kc < 4; ++kc) {
    if (kc) __syncthreads();
    {   // transpose-stage y[b][c][i] -> sY[i][c] (fp32 -> bf16)
      int cl = tid >> 4;
      int il = (tid & 15) * 4;
      #pragma unroll
      for (int p = 0; p < 4; ++p) {
        int c = kc * 64 + p * 16 + cl;
        float4 v = *(const float4*)(y + ((size_t)(b * 256 + c)) * 4096 + i0 + il);
        sY[(il + 0) * 72 + p * 16 + cl] = f2bf(v.x);
        sY[(il + 1) * 72 + p * 16 + cl] = f2bf(v.y);
        sY[(il + 2) * 72 + p * 16 + cl] = f2bf(v.z);
        sY[(il + 3) * 72 + p * 16 + cl] = f2bf(v.w);
      }
    }
    __syncthreads();
    #pragma unroll
    for (int kk = 0; kk < 2; ++kk) {
      bf16x8 af = ldb8(sY + (w * 16 + l16) * 72 + kk * 32 + quad * 8);
      #pragma unroll
      for (int f = 0; f < 16; ++f) {
        bf16x8 bfr = ldb8(qbp + (size_t)(f * 8 + kc * 2 + kk) * 512);
        acc[f] = MFMA16(af, bfr, acc[f]);
      }
    }
  }
  #pragma unroll
  for (int f = 0; f < 16; ++f) {
    int col = f * 16 + l16;
    float q0 = qb[col], sc = dww[col], dB = dwb[col];
    #pragma unroll
    for (int r = 0; r < 4; ++r) {
      int rowg = i0 + w * 16 + quad * 4 + r;
      float v = ((acc[f][r] + q0) * sc + dB) * QSCALE;
      Qb[((size_t)(b * 4096 + rowg)) * 256 + col] = f2bf(v);
    }
  }
}

// ---------- flash attention: round-5 version (fastest measured: 78.2 us) ----------
__global__ __launch_bounds__(256, 2) void k_attn(const u16* __restrict__ Qb, const u16* __restrict__ Kt,
    const u16* __restrict__ Vt, u16* __restrict__ Op, float* __restrict__ Ol) {
  __shared__ __align__(16) u16 smem[37888];
  int tid = threadIdx.x, w = tid >> 6, lane = tid & 63, quad = lane >> 4, l16 = lane & 15;
  int b = blockIdx.x & 3, kh = (blockIdx.x >> 2) & 3, qt = blockIdx.x >> 4;
  int i0 = qt * 128 + w * 32;

  bf16x8 qf[2][8];
  {
    const u16* qrow = Qb + ((size_t)(b * 4096 + i0 + l16)) * 256 + quad * 8;
    #pragma unroll
    for (int kk = 0; kk < 8; ++kk) {
      qf[0][kk] = ldb8(qrow + kk * 32);
      qf[1][kk] = ldb8(qrow + 16 * 256 + kk * 32);
    }
  }
  f32x4 z = {0.f, 0.f, 0.f, 0.f};
  f32x4 oacc[2][16];
  #pragma unroll
  for (int sub = 0; sub < 2; ++sub)
    #pragma unroll
    for (int f = 0; f < 16; ++f) oacc[sub][f] = z;
  float l4[2][4] = {{0.f, 0.f, 0.f, 0.f}, {0.f, 0.f, 0.f, 0.f}};

  u16* sPw = smem + 32768 + w * 1280;
  int wp = w & 1;
  const u16* gSrc = ((w < 2) ? Kt : Vt) + ((size_t)(b * 128 + kh * 32) * 8192) + wp * 4096 + lane * 8;
  u16* lBase = smem + ((w < 2) ? 0 : 8192) + wp * 4096 + lane * 8;

  #pragma unroll
  for (int i = 0; i < 8; ++i) gll16(gSrc + i * 512, lBase + i * 512);
  gSrc += 8192;

  #pragma unroll 1
  for (int kt = 0; kt < 32; ++kt) {
    int buf = kt & 1;
    const u16* sK = smem + buf * 16384;
    const u16* sV = sK + 8192;
    asm volatile("s_waitcnt vmcnt(0)" ::: "memory");
    __syncthreads();
    if (kt < 31) {
      u16* dst = lBase + (buf ^ 1) * 16384;
      #pragma unroll
      for (int i = 0; i < 8; ++i) gll16(gSrc + i * 512, dst + i * 512);
      gSrc += 8192;
    }
    f32x4 s00 = z, s01 = z, s10 = z, s11 = z;
    const u16* kb = sK + lane * 8;
    __builtin_amdgcn_s_setprio(1);
    #pragma unroll
    for (int kk = 0; kk < 8; ++kk) {
      bf16x8 k0 = ldb8(kb + kk * 1024);         // even kv columns
      bf16x8 k1 = ldb8(kb + kk * 1024 + 512);   // odd kv columns
      s00 = MFMA16(qf[0][kk], k0, s00);
      s01 = MFMA16(qf[0][kk], k1, s01);
      s10 = MFMA16(qf[1][kk], k0, s10);
      s11 = MFMA16(qf[1][kk], k1, s11);
    }
    __builtin_amdgcn_s_setprio(0);
    // s00[r]: S[qrow][kv=2*l16], s01[r]: kv=2*l16+1 -> u32 pack is natural kv order
    #pragma unroll
    for (int r = 0; r < 4; ++r) {
      float p0 = exp2f(s00[r]);
      float p1 = exp2f(s01[r]);
      float p2 = exp2f(s10[r]);
      float p3 = exp2f(s11[r]);
      l4[0][r] += p0 + p1;
      l4[1][r] += p2 + p3;
      unsigned pk0 = ((unsigned)bfc(p1) << 16) | (unsigned)bfc(p0);
      unsigned pk1 = ((unsigned)bfc(p3) << 16) | (unsigned)bfc(p2);
      int row0 = (quad * 4 + r) * 40;
      *(unsigned*)(sPw + row0 + l16 * 2) = pk0;
      *(unsigned*)(sPw + 640 + row0 + l16 * 2) = pk1;
    }
    asm volatile("s_waitcnt lgkmcnt(0)" ::: "memory");
    bf16x8 pf0 = ldb8(sPw + l16 * 40 + quad * 8);
    bf16x8 pf1 = ldb8(sPw + 640 + l16 * 40 + quad * 8);
    const u16* vbase = sV + lane * 8;
    __builtin_amdgcn_s_setprio(1);
    #pragma unroll
    for (int f = 0; f < 16; ++f) {
      bf16x8 vf = ldb8(vbase + f * 512);
      oacc[0][f] = MFMA16(pf0, vf, oacc[0][f]);
      oacc[1][f] = MFMA16(pf1, vf, oacc[1][f]);
    }
    __builtin_amdgcn_s_setprio(0);
  }
  #pragma unroll
  for (int sub = 0; sub < 2; ++sub)
    #pragma unroll
    for (int r = 0; r < 4; ++r) l4[sub][r] = red_sum16(l4[sub][r]);
  #pragma unroll
  for (int sub = 0; sub < 2; ++sub)
    #pragma unroll
    for (int r = 0; r < 4; ++r) {
      size_t gr = (size_t)kh * 16384 + b * 4096 + i0 + sub * 16 + quad * 4 + r;
      u16* orow = Op + gr * 256;
      #pragma unroll
      for (int f = 0; f < 16; ++f) orow[f * 16 + l16] = f2bf(oacc[sub][f][r]);
      if (l16 == 0) Ol[gr] = l4[sub][r];
    }
}

// ---------- proj + residual: o-half blocks (128 out-ch) ----------
__global__ __launch_bounds__(256) void k_proj(const u16* __restrict__ Op, const float* __restrict__ Ol,
    const u16* __restrict__ Pw, const float* __restrict__ pb, const float* __restrict__ y,
    float* __restrict__ out) {
  __shared__ __align__(16) u16 sA[128 * 136];
  __shared__ __align__(16) u16 sB[64 * 136];
  __shared__ float sW[64];
  int tid = threadIdx.x, w = tid >> 6, lane = tid & 63, quad = lane >> 4, l16 = lane & 15;
  int i0 = blockIdx.x * 64, o0 = blockIdx.y * 128, b = blockIdx.z;
  if (tid < 64) {
    size_t gr = (size_t)b * 4096 + i0 + tid;
    float L = Ol[gr] + Ol[gr + 16384] + Ol[gr + 32768] + Ol[gr + 49152];
    sW[tid] = 1.f / L;
  }
  __syncthreads();
  f32x4 z = {0.f, 0.f, 0.f, 0.f};
  f32x4 acc[2][4] = {{z, z, z, z}, {z, z, z, z}};
  for (int kc = 0; kc < 2; ++kc) {
    if (kc) __syncthreads();
    #pragma unroll
    for (int p = 0; p < 8; ++p) {     // sA: Pw [128 o][128 k-half]
      int q = p * 256 + tid; int row = q >> 4, c8 = q & 15;
      *(uint4*)(sA + row * 136 + c8 * 8) = *(const uint4*)(Pw + ((size_t)(o0 + row)) * 256 + kc * 128 + c8 * 8);
    }
    #pragma unroll
    for (int p = 0; p < 4; ++p) {     // sB: merged H [64 i][128 k-half]
      int q = p * 256 + tid; int row = q >> 4, c8 = q & 15;
      size_t gr = (size_t)b * 4096 + i0 + row;
      const u16* hp = Op + gr * 256 + kc * 128 + c8 * 8;
      uint4 u0 = *(const uint4*)(hp);
      uint4 u1 = *(const uint4*)(hp + 4194304);
      uint4 u2 = *(const uint4*)(hp + 8388608);
      uint4 u3 = *(const uint4*)(hp + 12582912);
      float wr = sW[row];
      const u16* p0 = (const u16*)&u0; const u16* p1 = (const u16*)&u1;
      const u16* p2 = (const u16*)&u2; const u16* p3 = (const u16*)&u3;
      ushort8 ov;
      #pragma unroll
      for (int e = 0; e < 8; ++e) {
        float v = (b2f(p0[e]) + b2f(p1[e]) + b2f(p2[e]) + b2f(p3[e])) * wr;
        ov[e] = f2bf(v);
      }
      *(ushort8*)(sB + row * 136 + c8 * 8) = ov;
    }
    __syncthreads();
    #pragma unroll
    for (int kk = 0; kk < 4; ++kk) {
      bf16x8 af0 = ldb8(sA + (w * 16 + l16) * 136 + kk * 32 + quad * 8);
      bf16x8 af1 = ldb8(sA + (64 + w * 16 + l16) * 136 + kk * 32 + quad * 8);
      #pragma unroll
      for (int nb = 0; nb < 4; ++nb) {
        bf16x8 bfr = ldb8(sB + (nb * 16 + l16) * 136 + kk * 32 + quad * 8);
        acc[0][nb] = MFMA16(af0, bfr, acc[0][nb]);
        acc[1][nb] = MFMA16(af1, bfr, acc[1][nb]);
      }
    }
  }
  #pragma unroll
  for (int oc = 0; oc < 2; ++oc)
    #pragma unroll
    for (int nb = 0; nb < 4; ++nb)
      #pragma unroll
      for (int r = 0; r < 4; ++r) {
        int og = o0 + oc * 64 + w * 16 + quad * 4 + r;
        size_t idx = ((size_t)(b * 256 + og)) * 4096 + i0 + nb * 16 + l16;
        out[idx] = y[idx] + acc[oc][nb][r] + pb[og];
      }
}

extern "C" void kernel_launch(void* const* d_in, const int* in_sizes, int n_in,
                              void* d_out, int out_size, void* d_ws, size_t ws_size,
                              hipStream_t stream) {
  (void)in_sizes; (void)n_in; (void)out_size; (void)ws_size;
  const float* x     = (const float*)d_in[0];
  const float* y     = (const float*)d_in[1];
  const float* q_w   = (const float*)d_in[2];
  const float* q_b   = (const float*)d_in[3];
  const float* dw_w  = (const float*)d_in[4];
  const float* dw_b  = (const float*)d_in[5];
  const float* kv_w1 = (const float*)d_in[6];
  const float* kv_b1 = (const float*)d_in[7];
  const float* ln1_g = (const float*)d_in[8];
  const float* ln1_b = (const float*)d_in[9];
  const float* kv_w2 = (const float*)d_in[10];
  const float* kv_b2 = (const float*)d_in[11];
  const float* ln2_g = (const float*)d_in[12];
  const float* ln2_b = (const float*)d_in[13];
  const float* kv_w3 = (const float*)d_in[14];
  const float* kv_b3 = (const float*)d_in[15];
  const float* ln3_g = (const float*)d_in[16];
  const float* ln3_b = (const float*)d_in[17];
  const float* kv_w4 = (const float*)d_in[18];
  const float* kv_b4 = (const float*)d_in[19];
  const float* proj_w = (const float*)d_in[20];
  const float* proj_b = (const float*)d_in[21];
  float* out = (float*)d_out;
  unsigned char* ws = (unsigned char*)d_ws;

  u16* Wt2 = (u16*)(ws + 0);            // fragment files (new layouts)
  u16* Wt3 = (u16*)(ws + 65536);
  u16* Wt4 = (u16*)(ws + 196608);
  u16* Qw  = (u16*)(ws + 458752);
  u16* Pww = (u16*)(ws + 589824);
  u16* Qb  = (u16*)(ws + 9437184);      // 8 MB
  u16* Kt  = (u16*)(ws + 17825792);     // 8 MB (fragment layout)
  u16* Vt  = (u16*)(ws + 26214400);     // 8 MB (fragment layout)
  u16* Op  = (u16*)(ws + 34603008);     // [4][16384][256] bf16, 32 MB
  float* Ol = (float*)(ws + 68157440);  // [4][16384] f32

  k_prep<<<1408, 256, 0, stream>>>(kv_w2, kv_w3, kv_w4, q_w, proj_w, Wt2, Wt3, Wt4, Qw, Pww);
  k_fused<<<512, 256, 0, stream>>>(x, kv_w1, kv_b1, ln1_g, ln1_b,
                                   Wt2, kv_b2, ln2_g, ln2_b,
                                   Wt3, kv_b3, ln3_g, ln3_b,
                                   Wt4, kv_b4,
                                   y, Qw, q_b, dw_w, dw_b,
                                   Kt, Vt, Qb);
  k_attn<<<512, 256, 0, stream>>>(Qb, Kt, Vt, Op, Ol);
  k_proj<<<dim3(64, 2, 4), 256, 0, stream>>>(Op, Ol, Pww, proj_b, y, out);
}

// Round 9
// 233.965 us; speedup vs baseline: 1.2350x; 1.2350x over previous
//
#include <hip/hip_runtime.h>
#include <cstdint>
#include <cstddef>

using bf16   = __bf16;
using bf16x8 = __bf16 __attribute__((ext_vector_type(8)));
using f32x4  = float  __attribute__((ext_vector_type(4)));
using u16    = unsigned short;
using ushort8 = __attribute__((ext_vector_type(8))) unsigned short;

#define MFMA16(a, b, c) __builtin_amdgcn_mfma_f32_16x16x32_bf16(a, b, c, 0, 0, 0)

__device__ __forceinline__ u16 f2bf(float f) {
  union { float f; unsigned u; } v; v.f = f;
  unsigned r = v.u + 0x7fffu + ((v.u >> 16) & 1u);
  return (u16)(r >> 16);
}
__device__ __forceinline__ u16 bfc(float f) {
  union { float f; unsigned u; } v; v.f = f;
  return (u16)((v.u + 0x8000u) >> 16);
}
__device__ __forceinline__ float b2f(u16 h) {
  union { unsigned u; float f; } v; v.u = ((unsigned)h) << 16; return v.f;
}
__device__ __forceinline__ bf16x8 ldb8(const u16* p) { return *(const bf16x8*)p; }
__device__ __forceinline__ float red_sum16(float v) {
  v += __shfl_xor(v, 1, 64); v += __shfl_xor(v, 2, 64);
  v += __shfl_xor(v, 4, 64); v += __shfl_xor(v, 8, 64);
  return v;
}
__device__ __forceinline__ void gll16(const u16* g, u16* l) {
  __builtin_amdgcn_global_load_lds(
      (const __attribute__((address_space(1))) void*)g,
      (__attribute__((address_space(3))) void*)l, 16, 0, 0);
}

#define QSCALE 0.09016844005556021f  // C^-0.5 * log2(e)

// ---------- prep: weight converts/transposes (round-5 version, verified) ----------
__global__ void k_prep(const float* __restrict__ kv_w2, const float* __restrict__ kv_w3,
                       const float* __restrict__ kv_w4, const float* __restrict__ q_w,
                       const float* __restrict__ proj_w,
                       u16* __restrict__ Wt2, u16* __restrict__ Wt3, u16* __restrict__ Wt4,
                       u16* __restrict__ Qw, u16* __restrict__ Pww) {
  int idx = blockIdx.x * 256 + threadIdx.x;
  if (idx < 32768) {                    // kv_w2 [128][256] -> Wt2 [256][128]
    int n = idx >> 7, k = idx & 127;
    Wt2[idx] = f2bf(kv_w2[k * 256 + n]);
  } else if (idx < 98304) {             // kv_w3 [256][256] -> Wt3 [256][256]
    int j = idx - 32768, n = j >> 8, k = j & 255;
    Wt3[j] = f2bf(kv_w3[k * 256 + n]);
  } else if (idx < 229376) {            // kv_w4 [256][512] -> Wt4 [512][256]
    int j = idx - 98304, n = j >> 8, k = j & 255;
    Wt4[j] = f2bf(kv_w4[k * 512 + n]);
  } else if (idx < 294912) {            // q_w already [o][c]
    int j = idx - 229376;
    Qw[j] = f2bf(q_w[j]);
  } else if (idx < 360448) {
    int j = idx - 294912;
    Pww[j] = f2bf(proj_w[j]);
  }
}

// ---------- fused MLP helpers (round-5 versions, verified) ----------
__device__ __forceinline__ void ln_store(f32x4* acc, const float* __restrict__ bias,
    const float* __restrict__ g, const float* __restrict__ bb, u16* act,
    int w, int quad, int l16) {
  #pragma unroll
  for (int f = 0; f < 16; ++f) {
    float bv = bias[f * 16 + l16];
    acc[f][0] += bv; acc[f][1] += bv; acc[f][2] += bv; acc[f][3] += bv;
  }
  #pragma unroll
  for (int r = 0; r < 4; ++r) {
    float s = 0;
    #pragma unroll
    for (int f = 0; f < 16; ++f) s += acc[f][r];
    s = red_sum16(s);
    float mu = s * (1.f / 256.f);
    float vv = 0;
    #pragma unroll
    for (int f = 0; f < 16; ++f) { float d = acc[f][r] - mu; vv += d * d; }
    vv = red_sum16(vv);
    float inv = rsqrtf(vv * (1.f / 256.f) + 1e-5f);
    int rl = w * 16 + quad * 4 + r;
    #pragma unroll
    for (int f = 0; f < 16; ++f) {
      int col = f * 16 + l16;
      float o = (acc[f][r] - mu) * inv * g[col] + bb[col];
      o = o > 0.f ? o : 0.01f * o;
      act[rl * 264 + col] = f2bf(o);
    }
  }
}

template<int K>
__device__ __forceinline__ void mlp_layer(u16* act, u16* sW, const u16* __restrict__ Wt,
    const float* __restrict__ bias, const float* __restrict__ g, const float* __restrict__ bb,
    int tid, int w, int quad, int l16) {
  bf16x8 af[K / 32];
  #pragma unroll
  for (int kk = 0; kk < K / 32; ++kk) af[kk] = ldb8(act + (w * 16 + l16) * 264 + kk * 32 + quad * 8);
  f32x4 z = {0.f, 0.f, 0.f, 0.f};
  f32x4 acc[16];
  #pragma unroll
  for (int f = 0; f < 16; ++f) acc[f] = z;
  for (int nc = 0; nc < 8; ++nc) {
    __syncthreads();
    #pragma unroll
    for (int p = 0; p < K / 64; ++p) {
      int q = p * 256 + tid; int row = q / (K / 8), c8 = q % (K / 8);
      *(uint4*)(sW + row * 264 + c8 * 8) = *(const uint4*)(Wt + (size_t)(nc * 32 + row) * K + c8 * 8);
    }
    __syncthreads();
    #pragma unroll
    for (int nb = 0; nb < 2; ++nb) {
      int f = nc * 2 + nb;
      #pragma unroll
      for (int kk = 0; kk < K / 32; ++kk)
        acc[f] = MFMA16(af[kk], ldb8(sW + (nb * 16 + l16) * 264 + kk * 32 + quad * 8), acc[f]);
    }
  }
  ln_store(acc, bias, g, bb, act, w, quad, l16);
  __syncthreads();
}

__device__ __forceinline__ void mlp_layer4(u16* act, u16* sW, const u16* __restrict__ Wt4,
    const float* __restrict__ bias4, u16* __restrict__ Kt, u16* __restrict__ Vt,
    int i0, int tid, int w, int quad, int l16) {
  bf16x8 af[8];
  #pragma unroll
  for (int kk = 0; kk < 8; ++kk) af[kk] = ldb8(act + (w * 16 + l16) * 264 + kk * 32 + quad * 8);
  f32x4 z = {0.f, 0.f, 0.f, 0.f};
  for (int h = 0; h < 2; ++h) {
    f32x4 acc[16];
    #pragma unroll
    for (int f = 0; f < 16; ++f) acc[f] = z;
    for (int nc = 0; nc < 8; ++nc) {
      __syncthreads();
      #pragma unroll
      for (int p = 0; p < 4; ++p) {
        int q = p * 256 + tid; int row = q >> 5, c8 = q & 31;
        *(uint4*)(sW + row * 264 + c8 * 8) =
            *(const uint4*)(Wt4 + (size_t)(h * 256 + nc * 32 + row) * 256 + c8 * 8);
      }
      __syncthreads();
      #pragma unroll
      for (int nb = 0; nb < 2; ++nb) {
        int f = nc * 2 + nb;
        #pragma unroll
        for (int kk = 0; kk < 8; ++kk)
          acc[f] = MFMA16(af[kk], ldb8(sW + (nb * 16 + l16) * 264 + kk * 32 + quad * 8), acc[f]);
      }
    }
    // epilogue: silu.
    // K: fragment layout, per 32-kv tile, u16 index within the 8192-u16 tile:
    //      kk*1024 + blk*512 + qs*128 + (kv>>1)*8 + e   (blk = kv&1)  [verified round 5]
    // V: fragment layout, natural kv order [verified round 1].
    #pragma unroll
    for (int f = 0; f < 16; ++f) {
      int col = f * 16 + l16;
      float bv = bias4[h * 256 + col];
      if (h == 0) {
        int kk = f >> 1;
        int qs = (f & 1) * 2 + (l16 >> 3);
        int e  = l16 & 7;
        int l16base = (w & 1) * 8 + quad * 2;
        size_t tb = ((size_t)((i0 >> 5) + (w >> 1))) * 8192 + kk * 1024 + qs * 128 + e;
        #pragma unroll
        for (int r = 0; r < 4; ++r) {
          float v = acc[f][r] + bv;
          v = v / (1.f + __expf(-v));
          Kt[tb + (size_t)(r & 1) * 512 + (size_t)(l16base + (r >> 1)) * 8] = f2bf(v);
        }
      } else {
        int rowg0 = i0 + w * 16 + quad * 4;
        int bb2 = rowg0 >> 12;          // batch
        int tt = (rowg0 >> 5) & 127;    // 32-kv tile
        int qv = (rowg0 >> 3) & 3;      // quad within tile
        int e0 = rowg0 & 7;             // element base (0 or 4)
        ushort4 u;
        #pragma unroll
        for (int r = 0; r < 4; ++r) {
          float v = acc[f][r] + bv;
          v = v / (1.f + __expf(-v));
          ((u16*)&u)[r] = f2bf(v);
        }
        size_t off = ((size_t)(bb2 * 128 + tt)) * 8192 + f * 512 + qv * 128 + l16 * 8 + e0;
        *(ushort4*)(Vt + off) = u;
      }
    }
  }
}

// ---------- fused: [blocks 0..255] full KV-MLP per 64-row tile; [256..511] Q-GEMM ----------
__global__ __launch_bounds__(256, 2) void k_fused(
    const float* __restrict__ x, const float* __restrict__ w1, const float* __restrict__ bias1,
    const float* __restrict__ g1, const float* __restrict__ bb1,
    const u16* __restrict__ Wt2, const float* __restrict__ bias2,
    const float* __restrict__ g2, const float* __restrict__ bb2,
    const u16* __restrict__ Wt3, const float* __restrict__ bias3,
    const float* __restrict__ g3, const float* __restrict__ bb3,
    const u16* __restrict__ Wt4, const float* __restrict__ bias4,
    const float* __restrict__ y, const u16* __restrict__ Qw,
    const float* __restrict__ qb, const float* __restrict__ dww, const float* __restrict__ dwb,
    u16* __restrict__ Kt, u16* __restrict__ Vt, u16* __restrict__ Qb) {
  __shared__ __align__(16) u16 smem[25344];   // P0: act[64*264] + sW[32*264]; P1: sY+sB
  int tid = threadIdx.x, w = tid >> 6, lane = tid & 63, quad = lane >> 4, l16 = lane & 15;

  if (blockIdx.x < 256) {
    // ===== KV-MLP partition: rows i0..i0+64 through all 4 layers, LDS-resident =====
    u16* act = smem;              // [64][264]
    u16* sW  = smem + 16896;      // [32][264]
    int i0 = blockIdx.x * 64;
    {   // layer 1: scalar -> 128, LN, leaky. Thread: row w*16+(lane>>2), cols (lane&3)*32..
      int rloc = w * 16 + (lane >> 2);
      int c0 = (lane & 3) * 32;
      float xv = x[i0 + rloc];
      float t[32];
      float s = 0.f;
      #pragma unroll
      for (int j = 0; j < 32; ++j) { t[j] = xv * w1[c0 + j] + bias1[c0 + j]; s += t[j]; }
      s += __shfl_xor(s, 1, 64); s += __shfl_xor(s, 2, 64);
      float mu = s * (1.f / 128.f);
      float vv = 0.f;
      #pragma unroll
      for (int j = 0; j < 32; ++j) { float d = t[j] - mu; vv += d * d; }
      vv += __shfl_xor(vv, 1, 64); vv += __shfl_xor(vv, 2, 64);
      float inv = rsqrtf(vv * (1.f / 128.f) + 1e-5f);
      #pragma unroll
      for (int jo = 0; jo < 4; ++jo) {
        ushort8 pk;
        #pragma unroll
        for (int e = 0; e < 8; ++e) {
          int j = jo * 8 + e;
          float o = (t[j] - mu) * inv * g1[c0 + j] + bb1[c0 + j];
          o = o > 0.f ? o : 0.01f * o;
          pk[e] = f2bf(o);
        }
        *(ushort8*)(act + rloc * 264 + c0 + jo * 8) = pk;
      }
    }
    __syncthreads();
    mlp_layer<128>(act, sW, Wt2, bias2, g2, bb2, tid, w, quad, l16);
    mlp_layer<256>(act, sW, Wt3, bias3, g3, bb3, tid, w, quad, l16);
    mlp_layer4(act, sW, Wt4, bias4, Kt, Vt, i0, tid, w, quad, l16);
    return;
  }

  // ===== Q-GEMM partition (independent of MLP): 64-row tiles, pre-scaled by QSCALE =====
  u16* sY = smem;              // [64][72]
  u16* sB = smem + 4608;       // [256][72]
  int t = blockIdx.x - 256;
  int b = t >> 6, i0 = (t & 63) * 64;
  f32x4 z = {0.f, 0.f, 0.f, 0.f};
  f32x4 acc[16];
  #pragma unroll
  for (int f = 0; f < 16; ++f) acc[f] = z;
  for (int kc = 0; kc < 4; ++kc) {
    if (kc) __syncthreads();
    {   // transpose-stage y[b][c][i] -> sY[i][c] (fp32 -> bf16)
      int cl = tid >> 4;
      int il = (tid & 15) * 4;
      #pragma unroll
      for (int p = 0; p < 4; ++p) {
        int c = kc * 64 + p * 16 + cl;
        float4 v = *(const float4*)(y + ((size_t)(b * 256 + c)) * 4096 + i0 + il);
        sY[(il + 0) * 72 + p * 16 + cl] = f2bf(v.x);
        sY[(il + 1) * 72 + p * 16 + cl] = f2bf(v.y);
        sY[(il + 2) * 72 + p * 16 + cl] = f2bf(v.z);
        sY[(il + 3) * 72 + p * 16 + cl] = f2bf(v.w);
      }
    }
    #pragma unroll
    for (int p = 0; p < 8; ++p) {
      int q = p * 256 + tid; int row = q >> 3, k8 = q & 7;
      *(uint4*)(sB + row * 72 + k8 * 8) = *(const uint4*)(Qw + (size_t)row * 256 + kc * 64 + k8 * 8);
    }
    __syncthreads();
    #pragma unroll
    for (int kk = 0; kk < 2; ++kk) {
      bf16x8 af = ldb8(sY + (w * 16 + l16) * 72 + kk * 32 + quad * 8);
      #pragma unroll
      for (int f = 0; f < 16; ++f) {
        bf16x8 bfr = ldb8(sB + (f * 16 + l16) * 72 + kk * 32 + quad * 8);
        acc[f] = MFMA16(af, bfr, acc[f]);
      }
    }
  }
  #pragma unroll
  for (int f = 0; f < 16; ++f) {
    int col = f * 16 + l16;
    float q0 = qb[col], sc = dww[col], dB = dwb[col];
    #pragma unroll
    for (int r = 0; r < 4; ++r) {
      int rowg = i0 + w * 16 + quad * 4 + r;
      float v = ((acc[f][r] + q0) * sc + dB) * QSCALE;
      Qb[((size_t)(b * 4096 + rowg)) * 256 + col] = f2bf(v);
    }
  }
}

// ---------- flash attention: round-5 version (fastest measured: 78.2 us) ----------
__global__ __launch_bounds__(256, 2) void k_attn(const u16* __restrict__ Qb, const u16* __restrict__ Kt,
    const u16* __restrict__ Vt, u16* __restrict__ Op, float* __restrict__ Ol) {
  __shared__ __align__(16) u16 smem[37888];
  int tid = threadIdx.x, w = tid >> 6, lane = tid & 63, quad = lane >> 4, l16 = lane & 15;
  int b = blockIdx.x & 3, kh = (blockIdx.x >> 2) & 3, qt = blockIdx.x >> 4;
  int i0 = qt * 128 + w * 32;

  bf16x8 qf[2][8];
  {
    const u16* qrow = Qb + ((size_t)(b * 4096 + i0 + l16)) * 256 + quad * 8;
    #pragma unroll
    for (int kk = 0; kk < 8; ++kk) {
      qf[0][kk] = ldb8(qrow + kk * 32);
      qf[1][kk] = ldb8(qrow + 16 * 256 + kk * 32);
    }
  }
  f32x4 z = {0.f, 0.f, 0.f, 0.f};
  f32x4 oacc[2][16];
  #pragma unroll
  for (int sub = 0; sub < 2; ++sub)
    #pragma unroll
    for (int f = 0; f < 16; ++f) oacc[sub][f] = z;
  float l4[2][4] = {{0.f, 0.f, 0.f, 0.f}, {0.f, 0.f, 0.f, 0.f}};

  u16* sPw = smem + 32768 + w * 1280;
  int wp = w & 1;
  const u16* gSrc = ((w < 2) ? Kt : Vt) + ((size_t)(b * 128 + kh * 32) * 8192) + wp * 4096 + lane * 8;
  u16* lBase = smem + ((w < 2) ? 0 : 8192) + wp * 4096 + lane * 8;

  #pragma unroll
  for (int i = 0; i < 8; ++i) gll16(gSrc + i * 512, lBase + i * 512);
  gSrc += 8192;

  #pragma unroll 1
  for (int kt = 0; kt < 32; ++kt) {
    int buf = kt & 1;
    const u16* sK = smem + buf * 16384;
    const u16* sV = sK + 8192;
    asm volatile("s_waitcnt vmcnt(0)" ::: "memory");
    __syncthreads();
    if (kt < 31) {
      u16* dst = lBase + (buf ^ 1) * 16384;
      #pragma unroll
      for (int i = 0; i < 8; ++i) gll16(gSrc + i * 512, dst + i * 512);
      gSrc += 8192;
    }
    f32x4 s00 = z, s01 = z, s10 = z, s11 = z;
    const u16* kb = sK + lane * 8;
    __builtin_amdgcn_s_setprio(1);
    #pragma unroll
    for (int kk = 0; kk < 8; ++kk) {
      bf16x8 k0 = ldb8(kb + kk * 1024);         // even kv columns
      bf16x8 k1 = ldb8(kb + kk * 1024 + 512);   // odd kv columns
      s00 = MFMA16(qf[0][kk], k0, s00);
      s01 = MFMA16(qf[0][kk], k1, s01);
      s10 = MFMA16(qf[1][kk], k0, s10);
      s11 = MFMA16(qf[1][kk], k1, s11);
    }
    __builtin_amdgcn_s_setprio(0);
    // s00[r]: S[qrow][kv=2*l16], s01[r]: kv=2*l16+1 -> u32 pack is natural kv order
    #pragma unroll
    for (int r = 0; r < 4; ++r) {
      float p0 = exp2f(s00[r]);
      float p1 = exp2f(s01[r]);
      float p2 = exp2f(s10[r]);
      float p3 = exp2f(s11[r]);
      l4[0][r] += p0 + p1;
      l4[1][r] += p2 + p3;
      unsigned pk0 = ((unsigned)bfc(p1) << 16) | (unsigned)bfc(p0);
      unsigned pk1 = ((unsigned)bfc(p3) << 16) | (unsigned)bfc(p2);
      int row0 = (quad * 4 + r) * 40;
      *(unsigned*)(sPw + row0 + l16 * 2) = pk0;
      *(unsigned*)(sPw + 640 + row0 + l16 * 2) = pk1;
    }
    asm volatile("s_waitcnt lgkmcnt(0)" ::: "memory");
    bf16x8 pf0 = ldb8(sPw + l16 * 40 + quad * 8);
    bf16x8 pf1 = ldb8(sPw + 640 + l16 * 40 + quad * 8);
    const u16* vbase = sV + lane * 8;
    __builtin_amdgcn_s_setprio(1);
    #pragma unroll
    for (int f = 0; f < 16; ++f) {
      bf16x8 vf = ldb8(vbase + f * 512);
      oacc[0][f] = MFMA16(pf0, vf, oacc[0][f]);
      oacc[1][f] = MFMA16(pf1, vf, oacc[1][f]);
    }
    __builtin_amdgcn_s_setprio(0);
  }
  #pragma unroll
  for (int sub = 0; sub < 2; ++sub)
    #pragma unroll
    for (int r = 0; r < 4; ++r) l4[sub][r] = red_sum16(l4[sub][r]);
  #pragma unroll
  for (int sub = 0; sub < 2; ++sub)
    #pragma unroll
    for (int r = 0; r < 4; ++r) {
      size_t gr = (size_t)kh * 16384 + b * 4096 + i0 + sub * 16 + quad * 4 + r;
      u16* orow = Op + gr * 256;
      #pragma unroll
      for (int f = 0; f < 16; ++f) orow[f * 16 + l16] = f2bf(oacc[sub][f][r]);
      if (l16 == 0) Ol[gr] = l4[sub][r];
    }
}

// ---------- proj + residual: 512 threads, 8 waves x one 16-row o-strip each.
// Same tiles/traffic/LDS as before; 16 waves/CU (was 8) for HBM latency hiding. ----------
__global__ __launch_bounds__(512) void k_proj(const u16* __restrict__ Op, const float* __restrict__ Ol,
    const u16* __restrict__ Pw, const float* __restrict__ pb, const float* __restrict__ y,
    float* __restrict__ out) {
  __shared__ __align__(16) u16 sA[128 * 136];
  __shared__ __align__(16) u16 sB[64 * 136];
  __shared__ float sW[64];
  int tid = threadIdx.x, w = tid >> 6, lane = tid & 63, quad = lane >> 4, l16 = lane & 15;
  int i0 = blockIdx.x * 64, o0 = blockIdx.y * 128, b = blockIdx.z;
  if (tid < 64) {
    size_t gr = (size_t)b * 4096 + i0 + tid;
    float L = Ol[gr] + Ol[gr + 16384] + Ol[gr + 32768] + Ol[gr + 49152];
    sW[tid] = 1.f / L;
  }
  __syncthreads();
  f32x4 z = {0.f, 0.f, 0.f, 0.f};
  f32x4 acc[4] = {z, z, z, z};
  for (int kc = 0; kc < 2; ++kc) {
    if (kc) __syncthreads();
    #pragma unroll
    for (int p = 0; p < 4; ++p) {     // sA: Pw [128 o][128 k-half], 2048 uint4 / 512 thr
      int q = p * 512 + tid; int row = q >> 4, c8 = q & 15;
      *(uint4*)(sA + row * 136 + c8 * 8) = *(const uint4*)(Pw + ((size_t)(o0 + row)) * 256 + kc * 128 + c8 * 8);
    }
    #pragma unroll
    for (int p = 0; p < 2; ++p) {     // sB: merged H [64 i][128 k-half], 1024 uint4 / 512 thr
      int q = p * 512 + tid; int row = q >> 4, c8 = q & 15;
      size_t gr = (size_t)b * 4096 + i0 + row;
      const u16* hp = Op + gr * 256 + kc * 128 + c8 * 8;
      uint4 u0 = *(const uint4*)(hp);
      uint4 u1 = *(const uint4*)(hp + 4194304);
      uint4 u2 = *(const uint4*)(hp + 8388608);
      uint4 u3 = *(const uint4*)(hp + 12582912);
      float wr = sW[row];
      const u16* p0 = (const u16*)&u0; const u16* p1 = (const u16*)&u1;
      const u16* p2 = (const u16*)&u2; const u16* p3 = (const u16*)&u3;
      ushort8 ov;
      #pragma unroll
      for (int e = 0; e < 8; ++e) {
        float v = (b2f(p0[e]) + b2f(p1[e]) + b2f(p2[e]) + b2f(p3[e])) * wr;
        ov[e] = f2bf(v);
      }
      *(ushort8*)(sB + row * 136 + c8 * 8) = ov;
    }
    __syncthreads();
    #pragma unroll
    for (int kk = 0; kk < 4; ++kk) {
      bf16x8 af = ldb8(sA + (w * 16 + l16) * 136 + kk * 32 + quad * 8);
      #pragma unroll
      for (int nb = 0; nb < 4; ++nb) {
        bf16x8 bfr = ldb8(sB + (nb * 16 + l16) * 136 + kk * 32 + quad * 8);
        acc[nb] = MFMA16(af, bfr, acc[nb]);
      }
    }
  }
  #pragma unroll
  for (int nb = 0; nb < 4; ++nb)
    #pragma unroll
    for (int r = 0; r < 4; ++r) {
      int og = o0 + w * 16 + quad * 4 + r;
      size_t idx = ((size_t)(b * 256 + og)) * 4096 + i0 + nb * 16 + l16;
      out[idx] = y[idx] + acc[nb][r] + pb[og];
    }
}

extern "C" void kernel_launch(void* const* d_in, const int* in_sizes, int n_in,
                              void* d_out, int out_size, void* d_ws, size_t ws_size,
                              hipStream_t stream) {
  (void)in_sizes; (void)n_in; (void)out_size; (void)ws_size;
  const float* x     = (const float*)d_in[0];
  const float* y     = (const float*)d_in[1];
  const float* q_w   = (const float*)d_in[2];
  const float* q_b   = (const float*)d_in[3];
  const float* dw_w  = (const float*)d_in[4];
  const float* dw_b  = (const float*)d_in[5];
  const float* kv_w1 = (const float*)d_in[6];
  const float* kv_b1 = (const float*)d_in[7];
  const float* ln1_g = (const float*)d_in[8];
  const float* ln1_b = (const float*)d_in[9];
  const float* kv_w2 = (const float*)d_in[10];
  const float* kv_b2 = (const float*)d_in[11];
  const float* ln2_g = (const float*)d_in[12];
  const float* ln2_b = (const float*)d_in[13];
  const float* kv_w3 = (const float*)d_in[14];
  const float* kv_b3 = (const float*)d_in[15];
  const float* ln3_g = (const float*)d_in[16];
  const float* ln3_b = (const float*)d_in[17];
  const float* kv_w4 = (const float*)d_in[18];
  const float* kv_b4 = (const float*)d_in[19];
  const float* proj_w = (const float*)d_in[20];
  const float* proj_b = (const float*)d_in[21];
  float* out = (float*)d_out;
  unsigned char* ws = (unsigned char*)d_ws;

  u16* Wt2 = (u16*)(ws + 0);
  u16* Wt3 = (u16*)(ws + 65536);
  u16* Wt4 = (u16*)(ws + 196608);
  u16* Qw  = (u16*)(ws + 458752);
  u16* Pww = (u16*)(ws + 589824);
  u16* Qb  = (u16*)(ws + 9437184);      // 8 MB
  u16* Kt  = (u16*)(ws + 17825792);     // 8 MB (fragment layout)
  u16* Vt  = (u16*)(ws + 26214400);     // 8 MB (fragment layout)
  u16* Op  = (u16*)(ws + 34603008);     // [4][16384][256] bf16, 32 MB
  float* Ol = (float*)(ws + 68157440);  // [4][16384] f32

  k_prep<<<1408, 256, 0, stream>>>(kv_w2, kv_w3, kv_w4, q_w, proj_w, Wt2, Wt3, Wt4, Qw, Pww);
  k_fused<<<512, 256, 0, stream>>>(x, kv_w1, kv_b1, ln1_g, ln1_b,
                                   Wt2, kv_b2, ln2_g, ln2_b,
                                   Wt3, kv_b3, ln3_g, ln3_b,
                                   Wt4, kv_b4,
                                   y, Qw, q_b, dw_w, dw_b,
                                   Kt, Vt, Qb);
  k_attn<<<512, 256, 0, stream>>>(Qb, Kt, Vt, Op, Ol);
  k_proj<<<dim3(64, 2, 4), 512, 0, stream>>>(Op, Ol, Pww, proj_b, y, out);
}

// Round 10
// 230.260 us; speedup vs baseline: 1.2549x; 1.0161x over previous
//
#include <hip/hip_runtime.h>
#include <cstdint>
#include <cstddef>

using bf16   = __bf16;
using bf16x8 = __bf16 __attribute__((ext_vector_type(8)));
using f32x4  = float  __attribute__((ext_vector_type(4)));
using u16    = unsigned short;
using ushort8 = __attribute__((ext_vector_type(8))) unsigned short;

#define MFMA16(a, b, c) __builtin_amdgcn_mfma_f32_16x16x32_bf16(a, b, c, 0, 0, 0)

__device__ __forceinline__ u16 f2bf(float f) {
  union { float f; unsigned u; } v; v.f = f;
  unsigned r = v.u + 0x7fffu + ((v.u >> 16) & 1u);
  return (u16)(r >> 16);
}
__device__ __forceinline__ u16 bfc(float f) {
  union { float f; unsigned u; } v; v.f = f;
  return (u16)((v.u + 0x8000u) >> 16);
}
__device__ __forceinline__ float b2f(u16 h) {
  union { unsigned u; float f; } v; v.u = ((unsigned)h) << 16; return v.f;
}
__device__ __forceinline__ bf16x8 ldb8(const u16* p) { return *(const bf16x8*)p; }
__device__ __forceinline__ float red_sum16(float v) {
  v += __shfl_xor(v, 1, 64); v += __shfl_xor(v, 2, 64);
  v += __shfl_xor(v, 4, 64); v += __shfl_xor(v, 8, 64);
  return v;
}
__device__ __forceinline__ void gll16(const u16* g, u16* l) {
  __builtin_amdgcn_global_load_lds(
      (const __attribute__((address_space(1))) void*)g,
      (__attribute__((address_space(3))) void*)l, 16, 0, 0);
}

#define QSCALE 0.09016844005556021f  // C^-0.5 * log2(e)

// ---------- prep: weight converts/transposes (round-5 version, verified) ----------
__global__ void k_prep(const float* __restrict__ kv_w2, const float* __restrict__ kv_w3,
                       const float* __restrict__ kv_w4, const float* __restrict__ q_w,
                       const float* __restrict__ proj_w,
                       u16* __restrict__ Wt2, u16* __restrict__ Wt3, u16* __restrict__ Wt4,
                       u16* __restrict__ Qw, u16* __restrict__ Pww) {
  int idx = blockIdx.x * 256 + threadIdx.x;
  if (idx < 32768) {                    // kv_w2 [128][256] -> Wt2 [256][128]
    int n = idx >> 7, k = idx & 127;
    Wt2[idx] = f2bf(kv_w2[k * 256 + n]);
  } else if (idx < 98304) {             // kv_w3 [256][256] -> Wt3 [256][256]
    int j = idx - 32768, n = j >> 8, k = j & 255;
    Wt3[j] = f2bf(kv_w3[k * 256 + n]);
  } else if (idx < 229376) {            // kv_w4 [256][512] -> Wt4 [512][256]
    int j = idx - 98304, n = j >> 8, k = j & 255;
    Wt4[j] = f2bf(kv_w4[k * 512 + n]);
  } else if (idx < 294912) {            // q_w already [o][c]
    int j = idx - 229376;
    Qw[j] = f2bf(q_w[j]);
  } else if (idx < 360448) {
    int j = idx - 294912;
    Pww[j] = f2bf(proj_w[j]);
  }
}

// ---------- fused MLP helpers ----------
__device__ __forceinline__ void ln_store(f32x4* acc, const float* __restrict__ bias,
    const float* __restrict__ g, const float* __restrict__ bb, u16* act,
    int w, int quad, int l16) {
  #pragma unroll
  for (int f = 0; f < 16; ++f) {
    float bv = bias[f * 16 + l16];
    acc[f][0] += bv; acc[f][1] += bv; acc[f][2] += bv; acc[f][3] += bv;
  }
  #pragma unroll
  for (int r = 0; r < 4; ++r) {
    float s = 0;
    #pragma unroll
    for (int f = 0; f < 16; ++f) s += acc[f][r];
    s = red_sum16(s);
    float mu = s * (1.f / 256.f);
    float vv = 0;
    #pragma unroll
    for (int f = 0; f < 16; ++f) { float d = acc[f][r] - mu; vv += d * d; }
    vv = red_sum16(vv);
    float inv = rsqrtf(vv * (1.f / 256.f) + 1e-5f);
    int rl = w * 16 + quad * 4 + r;
    #pragma unroll
    for (int f = 0; f < 16; ++f) {
      int col = f * 16 + l16;
      float o = (acc[f][r] - mu) * inv * g[col] + bb[col];
      o = o > 0.f ? o : 0.01f * o;
      act[rl * 264 + col] = f2bf(o);
    }
  }
}

// 64-col N-chunks (was 32): half the barriers, double the MFMA run length.
template<int K>
__device__ __forceinline__ void mlp_layer(u16* act, u16* sW, const u16* __restrict__ Wt,
    const float* __restrict__ bias, const float* __restrict__ g, const float* __restrict__ bb,
    int tid, int w, int quad, int l16) {
  bf16x8 af[K / 32];
  #pragma unroll
  for (int kk = 0; kk < K / 32; ++kk) af[kk] = ldb8(act + (w * 16 + l16) * 264 + kk * 32 + quad * 8);
  f32x4 z = {0.f, 0.f, 0.f, 0.f};
  f32x4 acc[16];
  #pragma unroll
  for (int f = 0; f < 16; ++f) acc[f] = z;
  for (int nc = 0; nc < 4; ++nc) {
    __syncthreads();
    #pragma unroll
    for (int p = 0; p < K / 32; ++p) {          // 64 rows x K cols = 64*K/8 uint4 / 256 thr
      int q = p * 256 + tid; int row = q / (K / 8), c8 = q % (K / 8);
      *(uint4*)(sW + row * 264 + c8 * 8) = *(const uint4*)(Wt + (size_t)(nc * 64 + row) * K + c8 * 8);
    }
    __syncthreads();
    #pragma unroll
    for (int nb = 0; nb < 4; ++nb) {
      int f = nc * 4 + nb;
      #pragma unroll
      for (int kk = 0; kk < K / 32; ++kk)
        acc[f] = MFMA16(af[kk], ldb8(sW + (nb * 16 + l16) * 264 + kk * 32 + quad * 8), acc[f]);
    }
  }
  ln_store(acc, bias, g, bb, act, w, quad, l16);
  __syncthreads();
}

__device__ __forceinline__ void mlp_layer4(u16* act, u16* sW, const u16* __restrict__ Wt4,
    const float* __restrict__ bias4, u16* __restrict__ Kt, u16* __restrict__ Vt,
    int i0, int tid, int w, int quad, int l16) {
  bf16x8 af[8];
  #pragma unroll
  for (int kk = 0; kk < 8; ++kk) af[kk] = ldb8(act + (w * 16 + l16) * 264 + kk * 32 + quad * 8);
  f32x4 z = {0.f, 0.f, 0.f, 0.f};
  for (int h = 0; h < 2; ++h) {
    f32x4 acc[16];
    #pragma unroll
    for (int f = 0; f < 16; ++f) acc[f] = z;
    for (int nc = 0; nc < 4; ++nc) {
      __syncthreads();
      #pragma unroll
      for (int p = 0; p < 8; ++p) {             // 64 rows x 256 cols = 2048 uint4 / 256 thr
        int q = p * 256 + tid; int row = q >> 5, c8 = q & 31;
        *(uint4*)(sW + row * 264 + c8 * 8) =
            *(const uint4*)(Wt4 + (size_t)(h * 256 + nc * 64 + row) * 256 + c8 * 8);
      }
      __syncthreads();
      #pragma unroll
      for (int nb = 0; nb < 4; ++nb) {
        int f = nc * 4 + nb;
        #pragma unroll
        for (int kk = 0; kk < 8; ++kk)
          acc[f] = MFMA16(af[kk], ldb8(sW + (nb * 16 + l16) * 264 + kk * 32 + quad * 8), acc[f]);
      }
    }
    // epilogue: silu.
    // K: fragment layout, per 32-kv tile, u16 index within the 8192-u16 tile:
    //      kk*1024 + blk*512 + qs*128 + (kv>>1)*8 + e   (blk = kv&1)  [verified round 5]
    // V: fragment layout, natural kv order [verified round 1].
    #pragma unroll
    for (int f = 0; f < 16; ++f) {
      int col = f * 16 + l16;
      float bv = bias4[h * 256 + col];
      if (h == 0) {
        int kk = f >> 1;
        int qs = (f & 1) * 2 + (l16 >> 3);
        int e  = l16 & 7;
        int l16base = (w & 1) * 8 + quad * 2;
        size_t tb = ((size_t)((i0 >> 5) + (w >> 1))) * 8192 + kk * 1024 + qs * 128 + e;
        #pragma unroll
        for (int r = 0; r < 4; ++r) {
          float v = acc[f][r] + bv;
          v = v / (1.f + __expf(-v));
          Kt[tb + (size_t)(r & 1) * 512 + (size_t)(l16base + (r >> 1)) * 8] = f2bf(v);
        }
      } else {
        int rowg0 = i0 + w * 16 + quad * 4;
        int bb2 = rowg0 >> 12;          // batch
        int tt = (rowg0 >> 5) & 127;    // 32-kv tile
        int qv = (rowg0 >> 3) & 3;      // quad within tile
        int e0 = rowg0 & 7;             // element base (0 or 4)
        ushort4 u;
        #pragma unroll
        for (int r = 0; r < 4; ++r) {
          float v = acc[f][r] + bv;
          v = v / (1.f + __expf(-v));
          ((u16*)&u)[r] = f2bf(v);
        }
        size_t off = ((size_t)(bb2 * 128 + tt)) * 8192 + f * 512 + qv * 128 + l16 * 8 + e0;
        *(ushort4*)(Vt + off) = u;
      }
    }
  }
}

// ---------- fused: [blocks 0..255] full KV-MLP per 64-row tile; [256..511] Q-GEMM ----------
__global__ __launch_bounds__(256, 2) void k_fused(
    const float* __restrict__ x, const float* __restrict__ w1, const float* __restrict__ bias1,
    const float* __restrict__ g1, const float* __restrict__ bb1,
    const u16* __restrict__ Wt2, const float* __restrict__ bias2,
    const float* __restrict__ g2, const float* __restrict__ bb2,
    const u16* __restrict__ Wt3, const float* __restrict__ bias3,
    const float* __restrict__ g3, const float* __restrict__ bb3,
    const u16* __restrict__ Wt4, const float* __restrict__ bias4,
    const float* __restrict__ y, const u16* __restrict__ Qw,
    const float* __restrict__ qb, const float* __restrict__ dww, const float* __restrict__ dwb,
    u16* __restrict__ Kt, u16* __restrict__ Vt, u16* __restrict__ Qb) {
  __shared__ __align__(16) u16 smem[33792];   // MLP: act[64*264] + sW[64*264]; QGEMM: sY+sB
  int tid = threadIdx.x, w = tid >> 6, lane = tid & 63, quad = lane >> 4, l16 = lane & 15;

  if (blockIdx.x < 256) {
    // ===== KV-MLP partition: rows i0..i0+64 through all 4 layers, LDS-resident =====
    u16* act = smem;              // [64][264]
    u16* sW  = smem + 16896;      // [64][264]
    int i0 = blockIdx.x * 64;
    {   // layer 1: scalar -> 128, LN, leaky. Thread: row w*16+(lane>>2), cols (lane&3)*32..
      int rloc = w * 16 + (lane >> 2);
      int c0 = (lane & 3) * 32;
      float xv = x[i0 + rloc];
      float t[32];
      float s = 0.f;
      #pragma unroll
      for (int j = 0; j < 32; ++j) { t[j] = xv * w1[c0 + j] + bias1[c0 + j]; s += t[j]; }
      s += __shfl_xor(s, 1, 64); s += __shfl_xor(s, 2, 64);
      float mu = s * (1.f / 128.f);
      float vv = 0.f;
      #pragma unroll
      for (int j = 0; j < 32; ++j) { float d = t[j] - mu; vv += d * d; }
      vv += __shfl_xor(vv, 1, 64); vv += __shfl_xor(vv, 2, 64);
      float inv = rsqrtf(vv * (1.f / 128.f) + 1e-5f);
      #pragma unroll
      for (int jo = 0; jo < 4; ++jo) {
        ushort8 pk;
        #pragma unroll
        for (int e = 0; e < 8; ++e) {
          int j = jo * 8 + e;
          float o = (t[j] - mu) * inv * g1[c0 + j] + bb1[c0 + j];
          o = o > 0.f ? o : 0.01f * o;
          pk[e] = f2bf(o);
        }
        *(ushort8*)(act + rloc * 264 + c0 + jo * 8) = pk;
      }
    }
    __syncthreads();
    mlp_layer<128>(act, sW, Wt2, bias2, g2, bb2, tid, w, quad, l16);
    mlp_layer<256>(act, sW, Wt3, bias3, g3, bb3, tid, w, quad, l16);
    mlp_layer4(act, sW, Wt4, bias4, Kt, Vt, i0, tid, w, quad, l16);
    return;
  }

  // ===== Q-GEMM partition (independent of MLP): 64-row tiles, pre-scaled by QSCALE =====
  u16* sY = smem;              // [64][72]
  u16* sB = smem + 4608;       // [256][72]
  int t = blockIdx.x - 256;
  int b = t >> 6, i0 = (t & 63) * 64;
  f32x4 z = {0.f, 0.f, 0.f, 0.f};
  f32x4 acc[16];
  #pragma unroll
  for (int f = 0; f < 16; ++f) acc[f] = z;
  for (int kc = 0; kc < 4; ++kc) {
    if (kc) __syncthreads();
    {   // transpose-stage y[b][c][i] -> sY[i][c] (fp32 -> bf16)
      int cl = tid >> 4;
      int il = (tid & 15) * 4;
      #pragma unroll
      for (int p = 0; p < 4; ++p) {
        int c = kc * 64 + p * 16 + cl;
        float4 v = *(const float4*)(y + ((size_t)(b * 256 + c)) * 4096 + i0 + il);
        sY[(il + 0) * 72 + p * 16 + cl] = f2bf(v.x);
        sY[(il + 1) * 72 + p * 16 + cl] = f2bf(v.y);
        sY[(il + 2) * 72 + p * 16 + cl] = f2bf(v.z);
        sY[(il + 3) * 72 + p * 16 + cl] = f2bf(v.w);
      }
    }
    #pragma unroll
    for (int p = 0; p < 8; ++p) {
      int q = p * 256 + tid; int row = q >> 3, k8 = q & 7;
      *(uint4*)(sB + row * 72 + k8 * 8) = *(const uint4*)(Qw + (size_t)row * 256 + kc * 64 + k8 * 8);
    }
    __syncthreads();
    #pragma unroll
    for (int kk = 0; kk < 2; ++kk) {
      bf16x8 af = ldb8(sY + (w * 16 + l16) * 72 + kk * 32 + quad * 8);
      #pragma unroll
      for (int f = 0; f < 16; ++f) {
        bf16x8 bfr = ldb8(sB + (f * 16 + l16) * 72 + kk * 32 + quad * 8);
        acc[f] = MFMA16(af, bfr, acc[f]);
      }
    }
  }
  #pragma unroll
  for (int f = 0; f < 16; ++f) {
    int col = f * 16 + l16;
    float q0 = qb[col], sc = dww[col], dB = dwb[col];
    #pragma unroll
    for (int r = 0; r < 4; ++r) {
      int rowg = i0 + w * 16 + quad * 4 + r;
      float v = ((acc[f][r] + q0) * sc + dB) * QSCALE;
      Qb[((size_t)(b * 4096 + rowg)) * 256 + col] = f2bf(v);
    }
  }
}

// ---------- flash attention: round-5 version (fastest measured: 78.2 us) ----------
__global__ __launch_bounds__(256, 2) void k_attn(const u16* __restrict__ Qb, const u16* __restrict__ Kt,
    const u16* __restrict__ Vt, u16* __restrict__ Op, float* __restrict__ Ol) {
  __shared__ __align__(16) u16 smem[37888];
  int tid = threadIdx.x, w = tid >> 6, lane = tid & 63, quad = lane >> 4, l16 = lane & 15;
  int b = blockIdx.x & 3, kh = (blockIdx.x >> 2) & 3, qt = blockIdx.x >> 4;
  int i0 = qt * 128 + w * 32;

  bf16x8 qf[2][8];
  {
    const u16* qrow = Qb + ((size_t)(b * 4096 + i0 + l16)) * 256 + quad * 8;
    #pragma unroll
    for (int kk = 0; kk < 8; ++kk) {
      qf[0][kk] = ldb8(qrow + kk * 32);
      qf[1][kk] = ldb8(qrow + 16 * 256 + kk * 32);
    }
  }
  f32x4 z = {0.f, 0.f, 0.f, 0.f};
  f32x4 oacc[2][16];
  #pragma unroll
  for (int sub = 0; sub < 2; ++sub)
    #pragma unroll
    for (int f = 0; f < 16; ++f) oacc[sub][f] = z;
  float l4[2][4] = {{0.f, 0.f, 0.f, 0.f}, {0.f, 0.f, 0.f, 0.f}};

  u16* sPw = smem + 32768 + w * 1280;
  int wp = w & 1;
  const u16* gSrc = ((w < 2) ? Kt : Vt) + ((size_t)(b * 128 + kh * 32) * 8192) + wp * 4096 + lane * 8;
  u16* lBase = smem + ((w < 2) ? 0 : 8192) + wp * 4096 + lane * 8;

  #pragma unroll
  for (int i = 0; i < 8; ++i) gll16(gSrc + i * 512, lBase + i * 512);
  gSrc += 8192;

  #pragma unroll 1
  for (int kt = 0; kt < 32; ++kt) {
    int buf = kt & 1;
    const u16* sK = smem + buf * 16384;
    const u16* sV = sK + 8192;
    asm volatile("s_waitcnt vmcnt(0)" ::: "memory");
    __syncthreads();
    if (kt < 31) {
      u16* dst = lBase + (buf ^ 1) * 16384;
      #pragma unroll
      for (int i = 0; i < 8; ++i) gll16(gSrc + i * 512, dst + i * 512);
      gSrc += 8192;
    }
    f32x4 s00 = z, s01 = z, s10 = z, s11 = z;
    const u16* kb = sK + lane * 8;
    __builtin_amdgcn_s_setprio(1);
    #pragma unroll
    for (int kk = 0; kk < 8; ++kk) {
      bf16x8 k0 = ldb8(kb + kk * 1024);         // even kv columns
      bf16x8 k1 = ldb8(kb + kk * 1024 + 512);   // odd kv columns
      s00 = MFMA16(qf[0][kk], k0, s00);
      s01 = MFMA16(qf[0][kk], k1, s01);
      s10 = MFMA16(qf[1][kk], k0, s10);
      s11 = MFMA16(qf[1][kk], k1, s11);
    }
    __builtin_amdgcn_s_setprio(0);
    // s00[r]: S[qrow][kv=2*l16], s01[r]: kv=2*l16+1 -> u32 pack is natural kv order
    #pragma unroll
    for (int r = 0; r < 4; ++r) {
      float p0 = exp2f(s00[r]);
      float p1 = exp2f(s01[r]);
      float p2 = exp2f(s10[r]);
      float p3 = exp2f(s11[r]);
      l4[0][r] += p0 + p1;
      l4[1][r] += p2 + p3;
      unsigned pk0 = ((unsigned)bfc(p1) << 16) | (unsigned)bfc(p0);
      unsigned pk1 = ((unsigned)bfc(p3) << 16) | (unsigned)bfc(p2);
      int row0 = (quad * 4 + r) * 40;
      *(unsigned*)(sPw + row0 + l16 * 2) = pk0;
      *(unsigned*)(sPw + 640 + row0 + l16 * 2) = pk1;
    }
    asm volatile("s_waitcnt lgkmcnt(0)" ::: "memory");
    bf16x8 pf0 = ldb8(sPw + l16 * 40 + quad * 8);
    bf16x8 pf1 = ldb8(sPw + 640 + l16 * 40 + quad * 8);
    const u16* vbase = sV + lane * 8;
    __builtin_amdgcn_s_setprio(1);
    #pragma unroll
    for (int f = 0; f < 16; ++f) {
      bf16x8 vf = ldb8(vbase + f * 512);
      oacc[0][f] = MFMA16(pf0, vf, oacc[0][f]);
      oacc[1][f] = MFMA16(pf1, vf, oacc[1][f]);
    }
    __builtin_amdgcn_s_setprio(0);
  }
  #pragma unroll
  for (int sub = 0; sub < 2; ++sub)
    #pragma unroll
    for (int r = 0; r < 4; ++r) l4[sub][r] = red_sum16(l4[sub][r]);
  #pragma unroll
  for (int sub = 0; sub < 2; ++sub)
    #pragma unroll
    for (int r = 0; r < 4; ++r) {
      size_t gr = (size_t)kh * 16384 + b * 4096 + i0 + sub * 16 + quad * 4 + r;
      u16* orow = Op + gr * 256;
      #pragma unroll
      for (int f = 0; f < 16; ++f) orow[f * 16 + l16] = f2bf(oacc[sub][f][r]);
      if (l16 == 0) Ol[gr] = l4[sub][r];
    }
}

// ---------- proj + residual: 512 threads, 8 waves x one 16-row o-strip each ----------
__global__ __launch_bounds__(512) void k_proj(const u16* __restrict__ Op, const float* __restrict__ Ol,
    const u16* __restrict__ Pw, const float* __restrict__ pb, const float* __restrict__ y,
    float* __restrict__ out) {
  __shared__ __align__(16) u16 sA[128 * 136];
  __shared__ __align__(16) u16 sB[64 * 136];
  __shared__ float sW[64];
  int tid = threadIdx.x, w = tid >> 6, lane = tid & 63, quad = lane >> 4, l16 = lane & 15;
  int i0 = blockIdx.x * 64, o0 = blockIdx.y * 128, b = blockIdx.z;
  if (tid < 64) {
    size_t gr = (size_t)b * 4096 + i0 + tid;
    float L = Ol[gr] + Ol[gr + 16384] + Ol[gr + 32768] + Ol[gr + 49152];
    sW[tid] = 1.f / L;
  }
  __syncthreads();
  f32x4 z = {0.f, 0.f, 0.f, 0.f};
  f32x4 acc[4] = {z, z, z, z};
  for (int kc = 0; kc < 2; ++kc) {
    if (kc) __syncthreads();
    #pragma unroll
    for (int p = 0; p < 4; ++p) {     // sA: Pw [128 o][128 k-half], 2048 uint4 / 512 thr
      int q = p * 512 + tid; int row = q >> 4, c8 = q & 15;
      *(uint4*)(sA + row * 136 + c8 * 8) = *(const uint4*)(Pw + ((size_t)(o0 + row)) * 256 + kc * 128 + c8 * 8);
    }
    #pragma unroll
    for (int p = 0; p < 2; ++p) {     // sB: merged H [64 i][128 k-half], 1024 uint4 / 512 thr
      int q = p * 512 + tid; int row = q >> 4, c8 = q & 15;
      size_t gr = (size_t)b * 4096 + i0 + row;
      const u16* hp = Op + gr * 256 + kc * 128 + c8 * 8;
      uint4 u0 = *(const uint4*)(hp);
      uint4 u1 = *(const uint4*)(hp + 4194304);
      uint4 u2 = *(const uint4*)(hp + 8388608);
      uint4 u3 = *(const uint4*)(hp + 12582912);
      float wr = sW[row];
      const u16* p0 = (const u16*)&u0; const u16* p1 = (const u16*)&u1;
      const u16* p2 = (const u16*)&u2; const u16* p3 = (const u16*)&u3;
      ushort8 ov;
      #pragma unroll
      for (int e = 0; e < 8; ++e) {
        float v = (b2f(p0[e]) + b2f(p1[e]) + b2f(p2[e]) + b2f(p3[e])) * wr;
        ov[e] = f2bf(v);
      }
      *(ushort8*)(sB + row * 136 + c8 * 8) = ov;
    }
    __syncthreads();
    #pragma unroll
    for (int kk = 0; kk < 4; ++kk) {
      bf16x8 af = ldb8(sA + (w * 16 + l16) * 136 + kk * 32 + quad * 8);
      #pragma unroll
      for (int nb = 0; nb < 4; ++nb) {
        bf16x8 bfr = ldb8(sB + (nb * 16 + l16) * 136 + kk * 32 + quad * 8);
        acc[nb] = MFMA16(af, bfr, acc[nb]);
      }
    }
  }
  #pragma unroll
  for (int nb = 0; nb < 4; ++nb)
    #pragma unroll
    for (int r = 0; r < 4; ++r) {
      int og = o0 + w * 16 + quad * 4 + r;
      size_t idx = ((size_t)(b * 256 + og)) * 4096 + i0 + nb * 16 + l16;
      out[idx] = y[idx] + acc[nb][r] + pb[og];
    }
}

extern "C" void kernel_launch(void* const* d_in, const int* in_sizes, int n_in,
                              void* d_out, int out_size, void* d_ws, size_t ws_size,
                              hipStream_t stream) {
  (void)in_sizes; (void)n_in; (void)out_size; (void)ws_size;
  const float* x     = (const float*)d_in[0];
  const float* y     = (const float*)d_in[1];
  const float* q_w   = (const float*)d_in[2];
  const float* q_b   = (const float*)d_in[3];
  const float* dw_w  = (const float*)d_in[4];
  const float* dw_b  = (const float*)d_in[5];
  const float* kv_w1 = (const float*)d_in[6];
  const float* kv_b1 = (const float*)d_in[7];
  const float* ln1_g = (const float*)d_in[8];
  const float* ln1_b = (const float*)d_in[9];
  const float* kv_w2 = (const float*)d_in[10];
  const float* kv_b2 = (const float*)d_in[11];
  const float* ln2_g = (const float*)d_in[12];
  const float* ln2_b = (const float*)d_in[13];
  const float* kv_w3 = (const float*)d_in[14];
  const float* kv_b3 = (const float*)d_in[15];
  const float* ln3_g = (const float*)d_in[16];
  const float* ln3_b = (const float*)d_in[17];
  const float* kv_w4 = (const float*)d_in[18];
  const float* kv_b4 = (const float*)d_in[19];
  const float* proj_w = (const float*)d_in[20];
  const float* proj_b = (const float*)d_in[21];
  float* out = (float*)d_out;
  unsigned char* ws = (unsigned char*)d_ws;

  u16* Wt2 = (u16*)(ws + 0);
  u16* Wt3 = (u16*)(ws + 65536);
  u16* Wt4 = (u16*)(ws + 196608);
  u16* Qw  = (u16*)(ws + 458752);
  u16* Pww = (u16*)(ws + 589824);
  u16* Qb  = (u16*)(ws + 9437184);      // 8 MB
  u16* Kt  = (u16*)(ws + 17825792);     // 8 MB (fragment layout)
  u16* Vt  = (u16*)(ws + 26214400);     // 8 MB (fragment layout)
  u16* Op  = (u16*)(ws + 34603008);     // [4][16384][256] bf16, 32 MB
  float* Ol = (float*)(ws + 68157440);  // [4][16384] f32

  k_prep<<<1408, 256, 0, stream>>>(kv_w2, kv_w3, kv_w4, q_w, proj_w, Wt2, Wt3, Wt4, Qw, Pww);
  k_fused<<<512, 256, 0, stream>>>(x, kv_w1, kv_b1, ln1_g, ln1_b,
                                   Wt2, kv_b2, ln2_g, ln2_b,
                                   Wt3, kv_b3, ln3_g, ln3_b,
                                   Wt4, kv_b4,
                                   y, Qw, q_b, dw_w, dw_b,
                                   Kt, Vt, Qb);
  k_attn<<<512, 256, 0, stream>>>(Qb, Kt, Vt, Op, Ol);
  k_proj<<<dim3(64, 2, 4), 512, 0, stream>>>(Op, Ol, Pww, proj_b, y, out);
}

// Round 11
// 228.975 us; speedup vs baseline: 1.2619x; 1.0056x over previous
//
#include <hip/hip_runtime.h>
#include <cstdint>
#include <cstddef>

using bf16   = __bf16;
using bf16x8 = __bf16 __attribute__((ext_vector_type(8)));
using f32x4  = float  __attribute__((ext_vector_type(4)));
using u16    = unsigned short;
using ushort8 = __attribute__((ext_vector_type(8))) unsigned short;

#define MFMA16(a, b, c) __builtin_amdgcn_mfma_f32_16x16x32_bf16(a, b, c, 0, 0, 0)

__device__ __forceinline__ u16 f2bf(float f) {
  union { float f; unsigned u; } v; v.f = f;
  unsigned r = v.u + 0x7fffu + ((v.u >> 16) & 1u);
  return (u16)(r >> 16);
}
__device__ __forceinline__ u16 bfc(float f) {
  union { float f; unsigned u; } v; v.f = f;
  return (u16)((v.u + 0x8000u) >> 16);
}
__device__ __forceinline__ float b2f(u16 h) {
  union { unsigned u; float f; } v; v.u = ((unsigned)h) << 16; return v.f;
}
__device__ __forceinline__ bf16x8 ldb8(const u16* p) { return *(const bf16x8*)p; }
__device__ __forceinline__ float red_sum16(float v) {
  v += __shfl_xor(v, 1, 64); v += __shfl_xor(v, 2, 64);
  v += __shfl_xor(v, 4, 64); v += __shfl_xor(v, 8, 64);
  return v;
}
__device__ __forceinline__ void gll16(const u16* g, u16* l) {
  __builtin_amdgcn_global_load_lds(
      (const __attribute__((address_space(1))) void*)g,
      (__attribute__((address_space(3))) void*)l, 16, 0, 0);
}

#define QSCALE 0.09016844005556021f  // C^-0.5 * log2(e)

// ---------- prep: weight converts/transposes.  Pww is now an MFMA A-fragment file
// (same verified convention as round-8 Qf): idx = ((f*8 + k8)*64 + l)*8 + e holds
// proj_w[o = f*16 + (l&15)][c = k8*32 + (l>>4)*8 + e]. ----------
__global__ void k_prep(const float* __restrict__ kv_w2, const float* __restrict__ kv_w3,
                       const float* __restrict__ kv_w4, const float* __restrict__ q_w,
                       const float* __restrict__ proj_w,
                       u16* __restrict__ Wt2, u16* __restrict__ Wt3, u16* __restrict__ Wt4,
                       u16* __restrict__ Qw, u16* __restrict__ Pww) {
  int idx = blockIdx.x * 256 + threadIdx.x;
  if (idx < 32768) {                    // kv_w2 [128][256] -> Wt2 [256][128]
    int n = idx >> 7, k = idx & 127;
    Wt2[idx] = f2bf(kv_w2[k * 256 + n]);
  } else if (idx < 98304) {             // kv_w3 [256][256] -> Wt3 [256][256]
    int j = idx - 32768, n = j >> 8, k = j & 255;
    Wt3[j] = f2bf(kv_w3[k * 256 + n]);
  } else if (idx < 229376) {            // kv_w4 [256][512] -> Wt4 [512][256]
    int j = idx - 98304, n = j >> 8, k = j & 255;
    Wt4[j] = f2bf(kv_w4[k * 512 + n]);
  } else if (idx < 294912) {            // q_w already [o][c]
    int j = idx - 229376;
    Qw[j] = f2bf(q_w[j]);
  } else if (idx < 360448) {            // proj_w [o][c] -> fragment file
    int j = idx - 294912, e = j & 7, l = (j >> 3) & 63, t = j >> 9;
    int k8 = t & 7, f = t >> 3;
    Pww[j] = f2bf(proj_w[(f * 16 + (l & 15)) * 256 + k8 * 32 + (l >> 4) * 8 + e]);
  }
}

// ---------- fused MLP helpers ----------
__device__ __forceinline__ void ln_store(f32x4* acc, const float* __restrict__ bias,
    const float* __restrict__ g, const float* __restrict__ bb, u16* act,
    int w, int quad, int l16) {
  #pragma unroll
  for (int f = 0; f < 16; ++f) {
    float bv = bias[f * 16 + l16];
    acc[f][0] += bv; acc[f][1] += bv; acc[f][2] += bv; acc[f][3] += bv;
  }
  #pragma unroll
  for (int r = 0; r < 4; ++r) {
    float s = 0;
    #pragma unroll
    for (int f = 0; f < 16; ++f) s += acc[f][r];
    s = red_sum16(s);
    float mu = s * (1.f / 256.f);
    float vv = 0;
    #pragma unroll
    for (int f = 0; f < 16; ++f) { float d = acc[f][r] - mu; vv += d * d; }
    vv = red_sum16(vv);
    float inv = rsqrtf(vv * (1.f / 256.f) + 1e-5f);
    int rl = w * 16 + quad * 4 + r;
    #pragma unroll
    for (int f = 0; f < 16; ++f) {
      int col = f * 16 + l16;
      float o = (acc[f][r] - mu) * inv * g[col] + bb[col];
      o = o > 0.f ? o : 0.01f * o;
      act[rl * 264 + col] = f2bf(o);
    }
  }
}

// 64-col N-chunks: half the barriers, double the MFMA run length (round 10, kept).
template<int K>
__device__ __forceinline__ void mlp_layer(u16* act, u16* sW, const u16* __restrict__ Wt,
    const float* __restrict__ bias, const float* __restrict__ g, const float* __restrict__ bb,
    int tid, int w, int quad, int l16) {
  bf16x8 af[K / 32];
  #pragma unroll
  for (int kk = 0; kk < K / 32; ++kk) af[kk] = ldb8(act + (w * 16 + l16) * 264 + kk * 32 + quad * 8);
  f32x4 z = {0.f, 0.f, 0.f, 0.f};
  f32x4 acc[16];
  #pragma unroll
  for (int f = 0; f < 16; ++f) acc[f] = z;
  for (int nc = 0; nc < 4; ++nc) {
    __syncthreads();
    #pragma unroll
    for (int p = 0; p < K / 32; ++p) {          // 64 rows x K cols = 64*K/8 uint4 / 256 thr
      int q = p * 256 + tid; int row = q / (K / 8), c8 = q % (K / 8);
      *(uint4*)(sW + row * 264 + c8 * 8) = *(const uint4*)(Wt + (size_t)(nc * 64 + row) * K + c8 * 8);
    }
    __syncthreads();
    #pragma unroll
    for (int nb = 0; nb < 4; ++nb) {
      int f = nc * 4 + nb;
      #pragma unroll
      for (int kk = 0; kk < K / 32; ++kk)
        acc[f] = MFMA16(af[kk], ldb8(sW + (nb * 16 + l16) * 264 + kk * 32 + quad * 8), acc[f]);
    }
  }
  ln_store(acc, bias, g, bb, act, w, quad, l16);
  __syncthreads();
}

__device__ __forceinline__ void mlp_layer4(u16* act, u16* sW, const u16* __restrict__ Wt4,
    const float* __restrict__ bias4, u16* __restrict__ Kt, u16* __restrict__ Vt,
    int i0, int tid, int w, int quad, int l16) {
  bf16x8 af[8];
  #pragma unroll
  for (int kk = 0; kk < 8; ++kk) af[kk] = ldb8(act + (w * 16 + l16) * 264 + kk * 32 + quad * 8);
  f32x4 z = {0.f, 0.f, 0.f, 0.f};
  for (int h = 0; h < 2; ++h) {
    f32x4 acc[16];
    #pragma unroll
    for (int f = 0; f < 16; ++f) acc[f] = z;
    for (int nc = 0; nc < 4; ++nc) {
      __syncthreads();
      #pragma unroll
      for (int p = 0; p < 8; ++p) {             // 64 rows x 256 cols = 2048 uint4 / 256 thr
        int q = p * 256 + tid; int row = q >> 5, c8 = q & 31;
        *(uint4*)(sW + row * 264 + c8 * 8) =
            *(const uint4*)(Wt4 + (size_t)(h * 256 + nc * 64 + row) * 256 + c8 * 8);
      }
      __syncthreads();
      #pragma unroll
      for (int nb = 0; nb < 4; ++nb) {
        int f = nc * 4 + nb;
        #pragma unroll
        for (int kk = 0; kk < 8; ++kk)
          acc[f] = MFMA16(af[kk], ldb8(sW + (nb * 16 + l16) * 264 + kk * 32 + quad * 8), acc[f]);
      }
    }
    // epilogue: silu.
    // K: fragment layout, per 32-kv tile, u16 index within the 8192-u16 tile:
    //      kk*1024 + blk*512 + qs*128 + (kv>>1)*8 + e   (blk = kv&1)  [verified round 5]
    // V: fragment layout, natural kv order [verified round 1].
    #pragma unroll
    for (int f = 0; f < 16; ++f) {
      int col = f * 16 + l16;
      float bv = bias4[h * 256 + col];
      if (h == 0) {
        int kk = f >> 1;
        int qs = (f & 1) * 2 + (l16 >> 3);
        int e  = l16 & 7;
        int l16base = (w & 1) * 8 + quad * 2;
        size_t tb = ((size_t)((i0 >> 5) + (w >> 1))) * 8192 + kk * 1024 + qs * 128 + e;
        #pragma unroll
        for (int r = 0; r < 4; ++r) {
          float v = acc[f][r] + bv;
          v = v / (1.f + __expf(-v));
          Kt[tb + (size_t)(r & 1) * 512 + (size_t)(l16base + (r >> 1)) * 8] = f2bf(v);
        }
      } else {
        int rowg0 = i0 + w * 16 + quad * 4;
        int bb2 = rowg0 >> 12;          // batch
        int tt = (rowg0 >> 5) & 127;    // 32-kv tile
        int qv = (rowg0 >> 3) & 3;      // quad within tile
        int e0 = rowg0 & 7;             // element base (0 or 4)
        ushort4 u;
        #pragma unroll
        for (int r = 0; r < 4; ++r) {
          float v = acc[f][r] + bv;
          v = v / (1.f + __expf(-v));
          ((u16*)&u)[r] = f2bf(v);
        }
        size_t off = ((size_t)(bb2 * 128 + tt)) * 8192 + f * 512 + qv * 128 + l16 * 8 + e0;
        *(ushort4*)(Vt + off) = u;
      }
    }
  }
}

// ---------- fused: [blocks 0..255] full KV-MLP per 64-row tile; [256..511] Q-GEMM ----------
__global__ __launch_bounds__(256, 2) void k_fused(
    const float* __restrict__ x, const float* __restrict__ w1, const float* __restrict__ bias1,
    const float* __restrict__ g1, const float* __restrict__ bb1,
    const u16* __restrict__ Wt2, const float* __restrict__ bias2,
    const float* __restrict__ g2, const float* __restrict__ bb2,
    const u16* __restrict__ Wt3, const float* __restrict__ bias3,
    const float* __restrict__ g3, const float* __restrict__ bb3,
    const u16* __restrict__ Wt4, const float* __restrict__ bias4,
    const float* __restrict__ y, const u16* __restrict__ Qw,
    const float* __restrict__ qb, const float* __restrict__ dww, const float* __restrict__ dwb,
    u16* __restrict__ Kt, u16* __restrict__ Vt, u16* __restrict__ Qb) {
  __shared__ __align__(16) u16 smem[33792];   // MLP: act[64*264] + sW[64*264]; QGEMM: sY+sB
  int tid = threadIdx.x, w = tid >> 6, lane = tid & 63, quad = lane >> 4, l16 = lane & 15;

  if (blockIdx.x < 256) {
    // ===== KV-MLP partition: rows i0..i0+64 through all 4 layers, LDS-resident =====
    u16* act = smem;              // [64][264]
    u16* sW  = smem + 16896;      // [64][264]
    int i0 = blockIdx.x * 64;
    {   // layer 1: scalar -> 128, LN, leaky. Thread: row w*16+(lane>>2), cols (lane&3)*32..
      int rloc = w * 16 + (lane >> 2);
      int c0 = (lane & 3) * 32;
      float xv = x[i0 + rloc];
      float t[32];
      float s = 0.f;
      #pragma unroll
      for (int j = 0; j < 32; ++j) { t[j] = xv * w1[c0 + j] + bias1[c0 + j]; s += t[j]; }
      s += __shfl_xor(s, 1, 64); s += __shfl_xor(s, 2, 64);
      float mu = s * (1.f / 128.f);
      float vv = 0.f;
      #pragma unroll
      for (int j = 0; j < 32; ++j) { float d = t[j] - mu; vv += d * d; }
      vv += __shfl_xor(vv, 1, 64); vv += __shfl_xor(vv, 2, 64);
      float inv = rsqrtf(vv * (1.f / 128.f) + 1e-5f);
      #pragma unroll
      for (int jo = 0; jo < 4; ++jo) {
        ushort8 pk;
        #pragma unroll
        for (int e = 0; e < 8; ++e) {
          int j = jo * 8 + e;
          float o = (t[j] - mu) * inv * g1[c0 + j] + bb1[c0 + j];
          o = o > 0.f ? o : 0.01f * o;
          pk[e] = f2bf(o);
        }
        *(ushort8*)(act + rloc * 264 + c0 + jo * 8) = pk;
      }
    }
    __syncthreads();
    mlp_layer<128>(act, sW, Wt2, bias2, g2, bb2, tid, w, quad, l16);
    mlp_layer<256>(act, sW, Wt3, bias3, g3, bb3, tid, w, quad, l16);
    mlp_layer4(act, sW, Wt4, bias4, Kt, Vt, i0, tid, w, quad, l16);
    return;
  }

  // ===== Q-GEMM partition (independent of MLP): 64-row tiles, pre-scaled by QSCALE =====
  u16* sY = smem;              // [64][72]
  u16* sB = smem + 4608;       // [256][72]
  int t = blockIdx.x - 256;
  int b = t >> 6, i0 = (t & 63) * 64;
  f32x4 z = {0.f, 0.f, 0.f, 0.f};
  f32x4 acc[16];
  #pragma unroll
  for (int f = 0; f < 16; ++f) acc[f] = z;
  for (int kc = 0; kc < 4; ++kc) {
    if (kc) __syncthreads();
    {   // transpose-stage y[b][c][i] -> sY[i][c] (fp32 -> bf16)
      int cl = tid >> 4;
      int il = (tid & 15) * 4;
      #pragma unroll
      for (int p = 0; p < 4; ++p) {
        int c = kc * 64 + p * 16 + cl;
        float4 v = *(const float4*)(y + ((size_t)(b * 256 + c)) * 4096 + i0 + il);
        sY[(il + 0) * 72 + p * 16 + cl] = f2bf(v.x);
        sY[(il + 1) * 72 + p * 16 + cl] = f2bf(v.y);
        sY[(il + 2) * 72 + p * 16 + cl] = f2bf(v.z);
        sY[(il + 3) * 72 + p * 16 + cl] = f2bf(v.w);
      }
    }
    #pragma unroll
    for (int p = 0; p < 8; ++p) {
      int q = p * 256 + tid; int row = q >> 3, k8 = q & 7;
      *(uint4*)(sB + row * 72 + k8 * 8) = *(const uint4*)(Qw + (size_t)row * 256 + kc * 64 + k8 * 8);
    }
    __syncthreads();
    #pragma unroll
    for (int kk = 0; kk < 2; ++kk) {
      bf16x8 af = ldb8(sY + (w * 16 + l16) * 72 + kk * 32 + quad * 8);
      #pragma unroll
      for (int f = 0; f < 16; ++f) {
        bf16x8 bfr = ldb8(sB + (f * 16 + l16) * 72 + kk * 32 + quad * 8);
        acc[f] = MFMA16(af, bfr, acc[f]);
      }
    }
  }
  #pragma unroll
  for (int f = 0; f < 16; ++f) {
    int col = f * 16 + l16;
    float q0 = qb[col], sc = dww[col], dB = dwb[col];
    #pragma unroll
    for (int r = 0; r < 4; ++r) {
      int rowg = i0 + w * 16 + quad * 4 + r;
      float v = ((acc[f][r] + q0) * sc + dB) * QSCALE;
      Qb[((size_t)(b * 4096 + rowg)) * 256 + col] = f2bf(v);
    }
  }
}

// ---------- flash attention: round-5 version (fastest measured: 78.2 us) ----------
__global__ __launch_bounds__(256, 2) void k_attn(const u16* __restrict__ Qb, const u16* __restrict__ Kt,
    const u16* __restrict__ Vt, u16* __restrict__ Op, float* __restrict__ Ol) {
  __shared__ __align__(16) u16 smem[37888];
  int tid = threadIdx.x, w = tid >> 6, lane = tid & 63, quad = lane >> 4, l16 = lane & 15;
  int b = blockIdx.x & 3, kh = (blockIdx.x >> 2) & 3, qt = blockIdx.x >> 4;
  int i0 = qt * 128 + w * 32;

  bf16x8 qf[2][8];
  {
    const u16* qrow = Qb + ((size_t)(b * 4096 + i0 + l16)) * 256 + quad * 8;
    #pragma unroll
    for (int kk = 0; kk < 8; ++kk) {
      qf[0][kk] = ldb8(qrow + kk * 32);
      qf[1][kk] = ldb8(qrow + 16 * 256 + kk * 32);
    }
  }
  f32x4 z = {0.f, 0.f, 0.f, 0.f};
  f32x4 oacc[2][16];
  #pragma unroll
  for (int sub = 0; sub < 2; ++sub)
    #pragma unroll
    for (int f = 0; f < 16; ++f) oacc[sub][f] = z;
  float l4[2][4] = {{0.f, 0.f, 0.f, 0.f}, {0.f, 0.f, 0.f, 0.f}};

  u16* sPw = smem + 32768 + w * 1280;
  int wp = w & 1;
  const u16* gSrc = ((w < 2) ? Kt : Vt) + ((size_t)(b * 128 + kh * 32) * 8192) + wp * 4096 + lane * 8;
  u16* lBase = smem + ((w < 2) ? 0 : 8192) + wp * 4096 + lane * 8;

  #pragma unroll
  for (int i = 0; i < 8; ++i) gll16(gSrc + i * 512, lBase + i * 512);
  gSrc += 8192;

  #pragma unroll 1
  for (int kt = 0; kt < 32; ++kt) {
    int buf = kt & 1;
    const u16* sK = smem + buf * 16384;
    const u16* sV = sK + 8192;
    asm volatile("s_waitcnt vmcnt(0)" ::: "memory");
    __syncthreads();
    if (kt < 31) {
      u16* dst = lBase + (buf ^ 1) * 16384;
      #pragma unroll
      for (int i = 0; i < 8; ++i) gll16(gSrc + i * 512, dst + i * 512);
      gSrc += 8192;
    }
    f32x4 s00 = z, s01 = z, s10 = z, s11 = z;
    const u16* kb = sK + lane * 8;
    __builtin_amdgcn_s_setprio(1);
    #pragma unroll
    for (int kk = 0; kk < 8; ++kk) {
      bf16x8 k0 = ldb8(kb + kk * 1024);         // even kv columns
      bf16x8 k1 = ldb8(kb + kk * 1024 + 512);   // odd kv columns
      s00 = MFMA16(qf[0][kk], k0, s00);
      s01 = MFMA16(qf[0][kk], k1, s01);
      s10 = MFMA16(qf[1][kk], k0, s10);
      s11 = MFMA16(qf[1][kk], k1, s11);
    }
    __builtin_amdgcn_s_setprio(0);
    // s00[r]: S[qrow][kv=2*l16], s01[r]: kv=2*l16+1 -> u32 pack is natural kv order
    #pragma unroll
    for (int r = 0; r < 4; ++r) {
      float p0 = exp2f(s00[r]);
      float p1 = exp2f(s01[r]);
      float p2 = exp2f(s10[r]);
      float p3 = exp2f(s11[r]);
      l4[0][r] += p0 + p1;
      l4[1][r] += p2 + p3;
      unsigned pk0 = ((unsigned)bfc(p1) << 16) | (unsigned)bfc(p0);
      unsigned pk1 = ((unsigned)bfc(p3) << 16) | (unsigned)bfc(p2);
      int row0 = (quad * 4 + r) * 40;
      *(unsigned*)(sPw + row0 + l16 * 2) = pk0;
      *(unsigned*)(sPw + 640 + row0 + l16 * 2) = pk1;
    }
    asm volatile("s_waitcnt lgkmcnt(0)" ::: "memory");
    bf16x8 pf0 = ldb8(sPw + l16 * 40 + quad * 8);
    bf16x8 pf1 = ldb8(sPw + 640 + l16 * 40 + quad * 8);
    const u16* vbase = sV + lane * 8;
    __builtin_amdgcn_s_setprio(1);
    #pragma unroll
    for (int f = 0; f < 16; ++f) {
      bf16x8 vf = ldb8(vbase + f * 512);
      oacc[0][f] = MFMA16(pf0, vf, oacc[0][f]);
      oacc[1][f] = MFMA16(pf1, vf, oacc[1][f]);
    }
    __builtin_amdgcn_s_setprio(0);
  }
  #pragma unroll
  for (int sub = 0; sub < 2; ++sub)
    #pragma unroll
    for (int r = 0; r < 4; ++r) l4[sub][r] = red_sum16(l4[sub][r]);
  #pragma unroll
  for (int sub = 0; sub < 2; ++sub)
    #pragma unroll
    for (int r = 0; r < 4; ++r) {
      size_t gr = (size_t)kh * 16384 + b * 4096 + i0 + sub * 16 + quad * 4 + r;
      u16* orow = Op + gr * 256;
      #pragma unroll
      for (int f = 0; f < 16; ++f) orow[f * 16 + l16] = f2bf(oacc[sub][f][r]);
      if (l16 == 0) Ol[gr] = l4[sub][r];
    }
}

// ---------- proj + residual: 512 blocks (128 i-tiles x 4 b) x 512 threads.
// All 256 o-channels per block (Op read ONCE, 32 MB not 64); Pw read direct-from-global
// as A-fragment file; only merged-H (32x264) + sW in LDS. 8 waves x 32 o-channels. ----------
__global__ __launch_bounds__(512) void k_proj(const u16* __restrict__ Op, const float* __restrict__ Ol,
    const u16* __restrict__ Pf, const float* __restrict__ pb, const float* __restrict__ y,
    float* __restrict__ out) {
  __shared__ __align__(16) u16 sB[32 * 264];
  __shared__ float sW[32];
  int tid = threadIdx.x, w = tid >> 6, lane = tid & 63, quad = lane >> 4, l16 = lane & 15;
  int i0 = blockIdx.x * 32, b = blockIdx.y;
  if (tid < 32) {
    size_t gr = (size_t)b * 4096 + i0 + tid;
    float L = Ol[gr] + Ol[gr + 16384] + Ol[gr + 32768] + Ol[gr + 49152];
    sW[tid] = 1.f / L;
  }
  __syncthreads();
  #pragma unroll
  for (int p = 0; p < 2; ++p) {       // merge H: [32 i][256 k] -> sB, 1024 uint4 / 512 thr
    int q = p * 512 + tid; int row = q >> 5, c8 = q & 31;
    size_t gr = (size_t)b * 4096 + i0 + row;
    const u16* hp = Op + gr * 256 + c8 * 8;
    uint4 u0 = *(const uint4*)(hp);
    uint4 u1 = *(const uint4*)(hp + 4194304);
    uint4 u2 = *(const uint4*)(hp + 8388608);
    uint4 u3 = *(const uint4*)(hp + 12582912);
    float wr = sW[row];
    const u16* p0 = (const u16*)&u0; const u16* p1 = (const u16*)&u1;
    const u16* p2 = (const u16*)&u2; const u16* p3 = (const u16*)&u3;
    ushort8 ov;
    #pragma unroll
    for (int e = 0; e < 8; ++e) {
      float v = (b2f(p0[e]) + b2f(p1[e]) + b2f(p2[e]) + b2f(p3[e])) * wr;
      ov[e] = f2bf(v);
    }
    *(ushort8*)(sB + row * 264 + c8 * 8) = ov;
  }
  __syncthreads();
  f32x4 z = {0.f, 0.f, 0.f, 0.f};
  f32x4 acc[2][2] = {{z, z}, {z, z}};
  const u16* pf0 = Pf + (size_t)((w * 2 + 0) * 8 * 64 + lane) * 8;
  const u16* pf1 = Pf + (size_t)((w * 2 + 1) * 8 * 64 + lane) * 8;
  #pragma unroll
  for (int kk = 0; kk < 8; ++kk) {
    bf16x8 b0 = ldb8(sB + l16 * 264 + kk * 32 + quad * 8);
    bf16x8 b1 = ldb8(sB + (16 + l16) * 264 + kk * 32 + quad * 8);
    bf16x8 a0 = ldb8(pf0 + (size_t)kk * 512);
    bf16x8 a1 = ldb8(pf1 + (size_t)kk * 512);
    acc[0][0] = MFMA16(a0, b0, acc[0][0]);
    acc[0][1] = MFMA16(a0, b1, acc[0][1]);
    acc[1][0] = MFMA16(a1, b0, acc[1][0]);
    acc[1][1] = MFMA16(a1, b1, acc[1][1]);
  }
  #pragma unroll
  for (int oc = 0; oc < 2; ++oc)
    #pragma unroll
    for (int nb = 0; nb < 2; ++nb)
      #pragma unroll
      for (int r = 0; r < 4; ++r) {
        int og = w * 32 + oc * 16 + quad * 4 + r;
        size_t idx = ((size_t)(b * 256 + og)) * 4096 + i0 + nb * 16 + l16;
        out[idx] = y[idx] + acc[oc][nb][r] + pb[og];
      }
}

extern "C" void kernel_launch(void* const* d_in, const int* in_sizes, int n_in,
                              void* d_out, int out_size, void* d_ws, size_t ws_size,
                              hipStream_t stream) {
  (void)in_sizes; (void)n_in; (void)out_size; (void)ws_size;
  const float* x     = (const float*)d_in[0];
  const float* y     = (const float*)d_in[1];
  const float* q_w   = (const float*)d_in[2];
  const float* q_b   = (const float*)d_in[3];
  const float* dw_w  = (const float*)d_in[4];
  const float* dw_b  = (const float*)d_in[5];
  const float* kv_w1 = (const float*)d_in[6];
  const float* kv_b1 = (const float*)d_in[7];
  const float* ln1_g = (const float*)d_in[8];
  const float* ln1_b = (const float*)d_in[9];
  const float* kv_w2 = (const float*)d_in[10];
  const float* kv_b2 = (const float*)d_in[11];
  const float* ln2_g = (const float*)d_in[12];
  const float* ln2_b = (const float*)d_in[13];
  const float* kv_w3 = (const float*)d_in[14];
  const float* kv_b3 = (const float*)d_in[15];
  const float* ln3_g = (const float*)d_in[16];
  const float* ln3_b = (const float*)d_in[17];
  const float* kv_w4 = (const float*)d_in[18];
  const float* kv_b4 = (const float*)d_in[19];
  const float* proj_w = (const float*)d_in[20];
  const float* proj_b = (const float*)d_in[21];
  float* out = (float*)d_out;
  unsigned char* ws = (unsigned char*)d_ws;

  u16* Wt2 = (u16*)(ws + 0);
  u16* Wt3 = (u16*)(ws + 65536);
  u16* Wt4 = (u16*)(ws + 196608);
  u16* Qw  = (u16*)(ws + 458752);
  u16* Pww = (u16*)(ws + 589824);       // A-fragment file
  u16* Qb  = (u16*)(ws + 9437184);      // 8 MB
  u16* Kt  = (u16*)(ws + 17825792);     // 8 MB (fragment layout)
  u16* Vt  = (u16*)(ws + 26214400);     // 8 MB (fragment layout)
  u16* Op  = (u16*)(ws + 34603008);     // [4][16384][256] bf16, 32 MB
  float* Ol = (float*)(ws + 68157440);  // [4][16384] f32

  k_prep<<<1408, 256, 0, stream>>>(kv_w2, kv_w3, kv_w4, q_w, proj_w, Wt2, Wt3, Wt4, Qw, Pww);
  k_fused<<<512, 256, 0, stream>>>(x, kv_w1, kv_b1, ln1_g, ln1_b,
                                   Wt2, kv_b2, ln2_g, ln2_b,
                                   Wt3, kv_b3, ln3_g, ln3_b,
                                   Wt4, kv_b4,
                                   y, Qw, q_b, dw_w, dw_b,
                                   Kt, Vt, Qb);
  k_attn<<<512, 256, 0, stream>>>(Qb, Kt, Vt, Op, Ol);
  k_proj<<<dim3(128, 4), 512, 0, stream>>>(Op, Ol, Pww, proj_b, y, out);
}